// Round 12
// baseline (677.534 us; speedup 1.0000x reference)
//
#include <hip/hip_runtime.h>
#include <hip/hip_bf16.h>

#define BB 64
#define NN 2000
#define GG 128
#define HH 128
#define NHEAD 8
#define HD 16

typedef __attribute__((ext_vector_type(8))) short short8;
typedef __attribute__((ext_vector_type(4))) float f32x4;

__device__ __forceinline__ unsigned short bf16hi(float f) {
    union { float f; unsigned u; } v; v.f = f;
    return (unsigned short)(v.u >> 16);
}
__device__ __forceinline__ float bf16tof(unsigned short h) {
    union { float f; unsigned u; } v; v.u = ((unsigned)h) << 16;
    return v.f;
}

// convert 8 fp32 (two float4) -> bf16 hi/lo short8 pair
__device__ __forceinline__ void cvt8(const float4& v0, const float4& v1,
                                     short8& hi, short8& lo) {
    float fv[8] = {v0.x, v0.y, v0.z, v0.w, v1.x, v1.y, v1.z, v1.w};
#pragma unroll
    for (int i = 0; i < 8; ++i) {
        unsigned short h = bf16hi(fv[i]);
        hi[i] = (short)h;
        lo[i] = (short)bf16hi(fv[i] - bf16tof(h));
    }
}

__device__ __forceinline__ void fma8x8(const float4& a0, const float4& a1,
                                       const float4& b0, const float4& b1,
                                       float acc[8][8]) {
    const float av[8] = {a0.x, a0.y, a0.z, a0.w, a1.x, a1.y, a1.z, a1.w};
    const float bv[8] = {b0.x, b0.y, b0.z, b0.w, b1.x, b1.y, b1.z, b1.w};
#pragma unroll
    for (int i = 0; i < 8; ++i)
#pragma unroll
        for (int k = 0; k < 8; ++k) acc[i][k] += av[i] * bv[k];
}

// ---- K1: transpose Wqg,Wqs,Wqt,Wql,Wc (fp32) + convert Wk,Wv to bf16 hi/lo ----
__global__ __launch_bounds__(256) void k_wt(const float* w0, const float* w1, const float* w2,
                     const float* w3, const float* w4, const float* w5,
                     const float* w6, float* WT,
                     unsigned short* Wkhi, unsigned short* Wklo,
                     unsigned short* Wvhi, unsigned short* Wvlo) {
    int m = blockIdx.x;
    if (m >= 5) {
        const float* src = (m == 5) ? w4 : w5;
        unsigned short* dh = (m == 5) ? Wkhi : Wvhi;
        unsigned short* dl = (m == 5) ? Wklo : Wvlo;
        for (int e = threadIdx.x * 4; e < 16384; e += 1024) {
            float4 v = *(const float4*)(src + e);
            float fv[4] = {v.x, v.y, v.z, v.w};
            unsigned short h4[4], l4[4];
#pragma unroll
            for (int i = 0; i < 4; ++i) {
                h4[i] = bf16hi(fv[i]); l4[i] = bf16hi(fv[i] - bf16tof(h4[i]));
            }
            uint2 ph, pl;
            ph.x = h4[0] | (h4[1] << 16); ph.y = h4[2] | (h4[3] << 16);
            pl.x = l4[0] | (l4[1] << 16); pl.y = l4[2] | (l4[3] << 16);
            *(uint2*)(dh + e) = ph;
            *(uint2*)(dl + e) = pl;
        }
        return;
    }
    __shared__ float t[128 * 129];
    const float* src = (m == 0) ? w0 : (m == 1) ? w1 : (m == 2) ? w2 : (m == 3) ? w3 : w6;
    int slot = (m == 4) ? 6 : m;
    for (int e = threadIdx.x; e < 16384; e += 256) {
        int c = e >> 7, j = e & 127;
        t[c * 129 + j] = src[e];
    }
    __syncthreads();
    for (int e = threadIdx.x; e < 16384; e += 256) {
        int j = e >> 7, c = e & 127;
        WT[slot * 16384 + e] = t[c * 129 + j];
    }
}

// ---- K2: mask -> bitmask ----
__global__ __launch_bounds__(256) void k_maskbits(const float* mask, unsigned long long* bits) {
    int bg = blockIdx.x;
    int lane = threadIdx.x & 63;
    int wv = threadIdx.x >> 6;
    for (int w = wv; w < 32; w += 4) {
        int n = w * 64 + lane;
        bool keep = false;
        if (n < NN) keep = (mask[(size_t)bg * NN + n] == 0.0f);
        unsigned long long bal = __ballot(keep);
        if (lane == 0) bits[bg * 32 + w] = bal;
    }
}

// ---- K3: partial column sums of embeddings ----
__global__ __launch_bounds__(128) void k_gsum(const float* emb, float* gpart) {
    int ck = blockIdx.x, b = blockIdx.y, c = threadIdx.x;
    const float* p = emb + ((size_t)b * NN + ck * 125) * HH + c;
    float s = 0.0f;
#pragma unroll 5
    for (int r = 0; r < 125; ++r) s += p[(size_t)r * HH];
    gpart[ck * 8192 + b * 128 + c] = s;
}

// ---- K4: qbase ----
__global__ __launch_bounds__(128) void k_qbase(const float* emb, const int* srcn, const int* tgtn,
                        const float* gpart, const float* WT, float* qbase) {
    int b = blockIdx.x, c = threadIdx.x;
    __shared__ float ge[128], se[128], te[128];
    float s = 0.0f;
#pragma unroll
    for (int t = 0; t < 16; ++t) s += gpart[t * 8192 + b * 128 + c];
    ge[c] = s * (1.0f / 2000.0f);
    se[c] = emb[((size_t)b * NN + srcn[b]) * HH + c];
    te[c] = emb[((size_t)b * NN + tgtn[b]) * HH + c];
    __syncthreads();
    const float* Wg = WT;
    const float* Ws = WT + 16384;
    const float* Wt2 = WT + 32768;
    float acc = 0.0f;
#pragma unroll 4
    for (int j = 0; j < 128; ++j) {
        acc += ge[j] * Wg[j * 128 + c] + se[j] * Ws[j * 128 + c] + te[j] * Wt2[j * 128 + c];
    }
    qbase[b * 128 + c] = acc;
}

// ---- K5: Qhl[b][g][128] (bf16 hi/lo) = 0.25*(qbase + lastemb@WqlT) ----
__global__ __launch_bounds__(256) void k_qlast(const float* emb, const int* lastn, const float* WT,
                        const float* qbase, unsigned short* Qhi, unsigned short* Qlo) {
    int b = blockIdx.x;
    int tid = threadIdx.x, xq = tid & 15, yq = tid >> 4;
    __shared__ float Bl[128 * 132];
    for (int e = tid; e < 16384; e += 256) {
        int g = e >> 7, j = e & 127;
        Bl[j * 132 + g] = emb[((size_t)b * NN + lastn[b * 128 + g]) * HH + j];
    }
    __syncthreads();
    const float* Wql = WT + 3 * 16384;
    float acc[8][8] = {};
#pragma unroll 4
    for (int j = 0; j < 128; ++j) {
        const float4* Ar = (const float4*)(Wql + j * 128);
        float4 a0 = Ar[yq], a1 = Ar[16 + yq];
        const float4* Br = (const float4*)(Bl + j * 132);
        float4 b0 = Br[xq], b1 = Br[16 + xq];
        fma8x8(a0, a1, b0, b1, acc);
    }
    float4 qb0 = *(const float4*)(qbase + b * 128 + 4 * yq);
    float4 qb1 = *(const float4*)(qbase + b * 128 + 64 + 4 * yq);
    const float q0v[4] = {qb0.x, qb0.y, qb0.z, qb0.w};
    const float q1v[4] = {qb1.x, qb1.y, qb1.z, qb1.w};
#pragma unroll
    for (int k = 0; k < 8; ++k) {
        int g = (k < 4) ? (4 * xq + k) : (64 + 4 * xq + (k - 4));
        size_t base = ((size_t)b * 128 + g) * 128;
        unsigned short h4[4], l4[4];
#pragma unroll
        for (int i = 0; i < 4; ++i) {
            float f = (acc[i][k] + q0v[i]) * 0.25f;
            h4[i] = bf16hi(f); l4[i] = bf16hi(f - bf16tof(h4[i]));
        }
        uint2 ph, pl;
        ph.x = h4[0] | (h4[1] << 16); ph.y = h4[2] | (h4[3] << 16);
        pl.x = l4[0] | (l4[1] << 16); pl.y = l4[2] | (l4[3] << 16);
        *(uint2*)(Qhi + base + 4 * yq) = ph;
        *(uint2*)(Qlo + base + 4 * yq) = pl;
#pragma unroll
        for (int i = 0; i < 4; ++i) {
            float f = (acc[4 + i][k] + q1v[i]) * 0.25f;
            h4[i] = bf16hi(f); l4[i] = bf16hi(f - bf16tof(h4[i]));
        }
        ph.x = h4[0] | (h4[1] << 16); ph.y = h4[2] | (h4[3] << 16);
        pl.x = l4[0] | (l4[1] << 16); pl.y = l4[2] | (l4[3] << 16);
        *(uint2*)(Qhi + base + 64 + 4 * yq) = ph;
        *(uint2*)(Qlo + base + 64 + 4 * yq) = pl;
    }
}

// ---- K6: K/V projections via split-bf16 MFMA; 128-n tile, no LDS, no barriers ----
__global__ __launch_bounds__(256, 4) void k_kv(const float* emb,
        const unsigned short* Wkhi, const unsigned short* Wklo,
        const unsigned short* Wvhi, const unsigned short* Wvlo,
        unsigned short* Khi, unsigned short* Klo,
        unsigned short* Vhi, unsigned short* Vlo) {
    int nt = blockIdx.x, b = blockIdx.y;  // nt in [0,16)
    int tid = threadIdx.x;
    int wv = tid >> 6, lane = tid & 63, l15 = lane & 15, q3 = lane >> 4;
    int n0 = nt * 128;

    short8 eh[2][4], el[2][4];
#pragma unroll
    for (int t = 0; t < 2; ++t) {
        int n = n0 + wv * 32 + t * 16 + l15;
        const float* rowp = emb + ((size_t)b * NN + n) * HH + q3 * 8;
        bool ok = (n < NN);
#pragma unroll
        for (int ks = 0; ks < 4; ++ks) {
            float4 v0 = make_float4(0.f, 0.f, 0.f, 0.f), v1 = v0;
            if (ok) {
                v0 = *(const float4*)(rowp + ks * 32);
                v1 = *(const float4*)(rowp + ks * 32 + 4);
            }
            cvt8(v0, v1, eh[t][ks], el[t][ks]);
        }
    }

#pragma unroll
    for (int ct = 0; ct < 8; ++ct) {
        f32x4 aK[2] = {{0.f, 0.f, 0.f, 0.f}, {0.f, 0.f, 0.f, 0.f}};
        f32x4 aV[2] = {{0.f, 0.f, 0.f, 0.f}, {0.f, 0.f, 0.f, 0.f}};
#pragma unroll
        for (int ks = 0; ks < 4; ++ks) {
            size_t woff = ((size_t)(ct * 16 + l15)) * 128 + ks * 32 + q3 * 8;
            short8 wkh = *(const short8*)(Wkhi + woff);
            short8 wkl = *(const short8*)(Wklo + woff);
            short8 wvh = *(const short8*)(Wvhi + woff);
            short8 wvl = *(const short8*)(Wvlo + woff);
#pragma unroll
            for (int t = 0; t < 2; ++t) {
                aK[t] = __builtin_amdgcn_mfma_f32_16x16x32_bf16(wkh, eh[t][ks], aK[t], 0, 0, 0);
                aK[t] = __builtin_amdgcn_mfma_f32_16x16x32_bf16(wkh, el[t][ks], aK[t], 0, 0, 0);
                aK[t] = __builtin_amdgcn_mfma_f32_16x16x32_bf16(wkl, eh[t][ks], aK[t], 0, 0, 0);
                aV[t] = __builtin_amdgcn_mfma_f32_16x16x32_bf16(eh[t][ks], wvh, aV[t], 0, 0, 0);
                aV[t] = __builtin_amdgcn_mfma_f32_16x16x32_bf16(el[t][ks], wvh, aV[t], 0, 0, 0);
                aV[t] = __builtin_amdgcn_mfma_f32_16x16x32_bf16(eh[t][ks], wvl, aV[t], 0, 0, 0);
            }
        }
#pragma unroll
        for (int t = 0; t < 2; ++t) {
            int kn = n0 + wv * 32 + t * 16 + l15;
            if (kn < NN) {
                unsigned short h4[4], l4[4];
#pragma unroll
                for (int r = 0; r < 4; ++r) {
                    float f = aK[t][r];
                    h4[r] = bf16hi(f); l4[r] = bf16hi(f - bf16tof(h4[r]));
                }
                uint2 ph, pl;
                ph.x = h4[0] | (h4[1] << 16); ph.y = h4[2] | (h4[3] << 16);
                pl.x = l4[0] | (l4[1] << 16); pl.y = l4[2] | (l4[3] << 16);
                size_t kbase = (((size_t)b * 8 + ct) * 2000 + kn) * 16 + 4 * q3;
                *(uint2*)(Khi + kbase) = ph;
                *(uint2*)(Klo + kbase) = pl;
            }
            int nb = n0 + wv * 32 + t * 16 + 4 * q3;
            if (nb + 3 < NN) {
                unsigned short h4[4], l4[4];
#pragma unroll
                for (int r = 0; r < 4; ++r) {
                    float f = aV[t][r];
                    h4[r] = bf16hi(f); l4[r] = bf16hi(f - bf16tof(h4[r]));
                }
                uint2 ph, pl;
                ph.x = h4[0] | (h4[1] << 16); ph.y = h4[2] | (h4[3] << 16);
                pl.x = l4[0] | (l4[1] << 16); pl.y = l4[2] | (l4[3] << 16);
                size_t vbase = (((size_t)b * 8 + ct) * 16 + l15) * 2000 + nb;
                *(uint2*)(Vhi + vbase) = ph;
                *(uint2*)(Vlo + vbase) = pl;
            }
        }
    }
}

// ---- K7: MFMA flash attention; NO LDS, NO barriers. P redistribution via shfl. ----
// S^T = K·Q^T per 16-n tile: lane(l15,q3) reg r holds P[n=nt*16+4q3+r][g=gt*16+wv*32+l15].
// PV B-frag needs P[n=ks*32+8q3+j][g(l15)]: source lane 32*(q3&1)+l15 (+16), reg nt=2ks+(q3>>1).
// NOTE: out-of-range K/V loads MUST be zeroed — garbage bf16 can be NaN, and
// MFMA's NaN*0=NaN would poison Oacc through the masked P=0 entries (round-11 bug).
__global__ __launch_bounds__(256, 4) void k_flash(const unsigned short* Khi, const unsigned short* Klo,
                        const unsigned short* Vhi, const unsigned short* Vlo,
                        const unsigned short* Qhi, const unsigned short* Qlo,
                        const unsigned long long* bits, float* Opart, float* Zpart) {
    int bid = blockIdx.x;
    int s4 = bid & 3, h = (bid >> 2) & 7, b = bid >> 5;
    int tid = threadIdx.x;
    int wv = tid >> 6, lane = tid & 63, l15 = lane & 15, q3 = lane >> 4;

    const short8 z8 = {0, 0, 0, 0, 0, 0, 0, 0};

    short8 qf[2][2];
#pragma unroll
    for (int gt = 0; gt < 2; ++gt) {
        int g = wv * 32 + gt * 16 + l15;
        if (q3 < 2) {
            size_t off = ((size_t)b * 128 + g) * 128 + h * 16 + q3 * 8;
            qf[gt][0] = *(const short8*)(Qhi + off);
            qf[gt][1] = *(const short8*)(Qlo + off);
        } else {
            qf[gt][0] = z8; qf[gt][1] = z8;
        }
    }

    f32x4 Oacc[2] = {{0.f, 0.f, 0.f, 0.f}, {0.f, 0.f, 0.f, 0.f}};
    float zacc[2] = {0.f, 0.f};

    const unsigned long long* bb0 = bits + (((size_t)b * 128 + wv * 32 + l15) * 32);
    const unsigned long long* bb1 = bb0 + 16 * 32;

    size_t kvbase = ((size_t)b * 8 + h);
    const unsigned short* Kh = Khi + kvbase * 32000;
    const unsigned short* Kl = Klo + kvbase * 32000;
    const unsigned short* Vh = Vhi + kvbase * 32000;
    const unsigned short* Vl = Vlo + kvbase * 32000;

    int laneA = ((q3 & 1) << 5) + l15;  // source lane for j=0..3
    int laneB = laneA + 16;             // source lane for j=4..7
    bool hiSel = (q3 & 2) != 0;         // true -> take nt=2ks+1

    for (int ch = s4 * 8; ch < s4 * 8 + 8; ++ch) {
        int n0 = ch * 64;
        unsigned long long wm0 = bb0[ch];
        unsigned long long wm1 = bb1[ch];

        // --- QK^T + mask/exp + pack (per nt) ---
        unsigned hi0[4][2], hi1[4][2], lo0[4][2], lo1[4][2];
#pragma unroll
        for (int nt = 0; nt < 4; ++nt) {
            short8 kh = z8, kl = z8;
            int kn = n0 + nt * 16 + l15;
            if (q3 < 2 && kn < NN) {
                size_t koff = ((size_t)kn) * 16 + q3 * 8;
                kh = *(const short8*)(Kh + koff);
                kl = *(const short8*)(Kl + koff);
            }
#pragma unroll
            for (int gt = 0; gt < 2; ++gt) {
                f32x4 c = {0.f, 0.f, 0.f, 0.f};
                c = __builtin_amdgcn_mfma_f32_16x16x32_bf16(kh, qf[gt][0], c, 0, 0, 0);
                c = __builtin_amdgcn_mfma_f32_16x16x32_bf16(kh, qf[gt][1], c, 0, 0, 0);
                c = __builtin_amdgcn_mfma_f32_16x16x32_bf16(kl, qf[gt][0], c, 0, 0, 0);
                unsigned long long wm = gt ? wm1 : wm0;
                float p[4];
#pragma unroll
                for (int r = 0; r < 4; ++r) {
                    int sh = nt * 16 + q3 * 4 + r;
                    float e = ((wm >> sh) & 1ull) ? __expf(c[r]) : 0.0f;
                    p[r] = e;
                    zacc[gt] += e;
                }
                unsigned short h4[4], l4[4];
#pragma unroll
                for (int r = 0; r < 4; ++r) {
                    h4[r] = bf16hi(p[r]); l4[r] = bf16hi(p[r] - bf16tof(h4[r]));
                }
                hi0[nt][gt] = (unsigned)h4[0] | ((unsigned)h4[1] << 16);
                hi1[nt][gt] = (unsigned)h4[2] | ((unsigned)h4[3] << 16);
                lo0[nt][gt] = (unsigned)l4[0] | ((unsigned)l4[1] << 16);
                lo1[nt][gt] = (unsigned)l4[2] | ((unsigned)l4[3] << 16);
            }
        }

        // --- PV with shfl redistribution ---
#pragma unroll
        for (int ks = 0; ks < 2; ++ks) {
            short8 vh = z8, vl = z8;
            int vn = n0 + ks * 32 + q3 * 8;  // 8-aligned; NN=2000 is 8-aligned -> full-vector check
            if (vn < NN) {
                size_t voff = (size_t)l15 * 2000 + vn;
                vh = *(const short8*)(Vh + voff);
                vl = *(const short8*)(Vl + voff);
            }
            int nta = 2 * ks, ntb = 2 * ks + 1;
#pragma unroll
            for (int gt = 0; gt < 2; ++gt) {
                uint4 hw, lw;
                {
                    unsigned a, bsh;
                    a = __shfl(hi0[nta][gt], laneA); bsh = __shfl(hi0[ntb][gt], laneA);
                    hw.x = hiSel ? bsh : a;
                    a = __shfl(hi1[nta][gt], laneA); bsh = __shfl(hi1[ntb][gt], laneA);
                    hw.y = hiSel ? bsh : a;
                    a = __shfl(hi0[nta][gt], laneB); bsh = __shfl(hi0[ntb][gt], laneB);
                    hw.z = hiSel ? bsh : a;
                    a = __shfl(hi1[nta][gt], laneB); bsh = __shfl(hi1[ntb][gt], laneB);
                    hw.w = hiSel ? bsh : a;
                    a = __shfl(lo0[nta][gt], laneA); bsh = __shfl(lo0[ntb][gt], laneA);
                    lw.x = hiSel ? bsh : a;
                    a = __shfl(lo1[nta][gt], laneA); bsh = __shfl(lo1[ntb][gt], laneA);
                    lw.y = hiSel ? bsh : a;
                    a = __shfl(lo0[nta][gt], laneB); bsh = __shfl(lo0[ntb][gt], laneB);
                    lw.z = hiSel ? bsh : a;
                    a = __shfl(lo1[nta][gt], laneB); bsh = __shfl(lo1[ntb][gt], laneB);
                    lw.w = hiSel ? bsh : a;
                }
                short8 ph = *(short8*)&hw;
                short8 pl = *(short8*)&lw;
                Oacc[gt] = __builtin_amdgcn_mfma_f32_16x16x32_bf16(vh, ph, Oacc[gt], 0, 0, 0);
                Oacc[gt] = __builtin_amdgcn_mfma_f32_16x16x32_bf16(vh, pl, Oacc[gt], 0, 0, 0);
                Oacc[gt] = __builtin_amdgcn_mfma_f32_16x16x32_bf16(vl, ph, Oacc[gt], 0, 0, 0);
            }
        }
    }

    size_t obase = (((size_t)s4 * 64 + b) * 8 + h);
#pragma unroll
    for (int gt = 0; gt < 2; ++gt) {
        float z = zacc[gt];
        z += __shfl_xor(z, 16);
        z += __shfl_xor(z, 32);
        int g = wv * 32 + gt * 16 + l15;
        if (q3 == 0) Zpart[obase * 128 + g] = z;
#pragma unroll
        for (int r = 0; r < 4; ++r) {
            int d = q3 * 4 + r;
            Opart[(obase * 16 + d) * 128 + g] = Oacc[gt][r];
        }
    }
}

// ---- K7b: combine partials -> MHt[b][h*16+d][g] ----
__global__ __launch_bounds__(256) void k_ocomb(const float* Opart, const float* Zpart, float* MHt) {
    int bh = blockIdx.x;
    int b = bh >> 3, h = bh & 7;
    int tid = threadIdx.x;
    for (int e = tid; e < 2048; e += 256) {
        int d = e >> 7, g = e & 127;
        float z = 0.0f, o = 0.0f;
#pragma unroll
        for (int s = 0; s < 4; ++s) {
            z += Zpart[(((size_t)s * 64 + b) * 8 + h) * 128 + g];
            o += Opart[((((size_t)s * 64 + b) * 8 + h) * 16 + d) * 128 + g];
        }
        MHt[((size_t)b * 128 + h * 16 + d) * 128 + g] = o / z;
    }
}

// ---- K8: FQhl[b][g][c] (bf16 hi/lo) = (MH[b][g]@WcT + bc)*rsqrt(H) ----
__global__ __launch_bounds__(256) void k_fq(const float* MHt, const float* WT, const float* bcv,
                                            unsigned short* FQhi, unsigned short* FQlo) {
    int b = blockIdx.x;
    int tid = threadIdx.x, xq = tid & 15, yq = tid >> 4;
    __shared__ float Bl[128 * 132];
    for (int e = tid; e < 16384; e += 256) {
        int j = e >> 7, g = e & 127;
        Bl[j * 132 + g] = MHt[(size_t)b * 16384 + e];
    }
    __syncthreads();
    const float* Wc = WT + 6 * 16384;
    float acc[8][8] = {};
#pragma unroll 4
    for (int j = 0; j < 128; ++j) {
        const float4* Ar = (const float4*)(Wc + j * 128);
        float4 a0 = Ar[yq], a1 = Ar[16 + yq];
        const float4* Br = (const float4*)(Bl + j * 132);
        float4 b0 = Br[xq], b1 = Br[16 + xq];
        fma8x8(a0, a1, b0, b1, acc);
    }
    float4 bc0 = *(const float4*)(bcv + 4 * yq);
    float4 bc1 = *(const float4*)(bcv + 64 + 4 * yq);
    const float bcv8[8] = {bc0.x, bc0.y, bc0.z, bc0.w, bc1.x, bc1.y, bc1.z, bc1.w};
    const float sc = 0.08838834764831845f;  // 1/sqrt(128)
#pragma unroll
    for (int k = 0; k < 8; ++k) {
        int g = (k < 4) ? (4 * xq + k) : (64 + 4 * xq + (k - 4));
        size_t base = ((size_t)b * 128 + g) * 128;
        unsigned short h4[4], l4[4];
#pragma unroll
        for (int i = 0; i < 4; ++i) {
            float f = (acc[i][k] + bcv8[i]) * sc;
            h4[i] = bf16hi(f); l4[i] = bf16hi(f - bf16tof(h4[i]));
        }
        uint2 ph, pl;
        ph.x = h4[0] | (h4[1] << 16); ph.y = h4[2] | (h4[3] << 16);
        pl.x = l4[0] | (l4[1] << 16); pl.y = l4[2] | (l4[3] << 16);
        *(uint2*)(FQhi + base + 4 * yq) = ph;
        *(uint2*)(FQlo + base + 4 * yq) = pl;
#pragma unroll
        for (int i = 0; i < 4; ++i) {
            float f = (acc[4 + i][k] + bcv8[4 + i]) * sc;
            h4[i] = bf16hi(f); l4[i] = bf16hi(f - bf16tof(h4[i]));
        }
        ph.x = h4[0] | (h4[1] << 16); ph.y = h4[2] | (h4[3] << 16);
        pl.x = l4[0] | (l4[1] << 16); pl.y = l4[2] | (l4[3] << 16);
        *(uint2*)(FQhi + base + 64 + 4 * yq) = ph;
        *(uint2*)(FQlo + base + 64 + 4 * yq) = pl;
    }
}

// ---- K9: logits via split-bf16 MFMA; swapped operands; no LDS, no barriers ----
__global__ __launch_bounds__(256, 4) void k_logits(const float* emb,
        const unsigned short* FQhi, const unsigned short* FQlo,
        const unsigned long long* bits, float* out, float* Zp) {
    int nt = blockIdx.x, b = blockIdx.y;  // nt in [0,16)
    int tid = threadIdx.x;
    int wv = tid >> 6, lane = tid & 63, l15 = lane & 15, q3 = lane >> 4;
    int n0 = nt * 128;

    short8 beh[2][4], bel[2][4];
#pragma unroll
    for (int t = 0; t < 2; ++t) {
        int n = n0 + wv * 32 + t * 16 + l15;
        const float* rowp = emb + ((size_t)b * NN + n) * HH + q3 * 8;
        bool ok = (n < NN);
#pragma unroll
        for (int ks = 0; ks < 4; ++ks) {
            float4 v0 = make_float4(0.f, 0.f, 0.f, 0.f), v1 = v0;
            if (ok) {
                v0 = *(const float4*)(rowp + ks * 32);
                v1 = *(const float4*)(rowp + ks * 32 + 4);
            }
            cvt8(v0, v1, beh[t][ks], bel[t][ks]);
        }
    }

    const unsigned long long* bb = bits + (size_t)b * 128 * 32;
    int g = 0;
#pragma unroll
    for (int gt = 0; gt < 8; ++gt) {
        f32x4 acc[2] = {{0.f, 0.f, 0.f, 0.f}, {0.f, 0.f, 0.f, 0.f}};
#pragma unroll
        for (int ks = 0; ks < 4; ++ks) {
            size_t foff = ((size_t)b * 128 + gt * 16 + l15) * 128 + ks * 32 + q3 * 8;
            short8 fh = *(const short8*)(FQhi + foff);
            short8 fl = *(const short8*)(FQlo + foff);
#pragma unroll
            for (int t = 0; t < 2; ++t) {
                acc[t] = __builtin_amdgcn_mfma_f32_16x16x32_bf16(beh[t][ks], fh, acc[t], 0, 0, 0);
                acc[t] = __builtin_amdgcn_mfma_f32_16x16x32_bf16(bel[t][ks], fh, acc[t], 0, 0, 0);
                acc[t] = __builtin_amdgcn_mfma_f32_16x16x32_bf16(beh[t][ks], fl, acc[t], 0, 0, 0);
            }
        }
        g = gt * 16 + l15;
        float psum = 0.f;
#pragma unroll
        for (int t = 0; t < 2; ++t) {
            int nb = n0 + wv * 32 + t * 16 + 4 * q3;
            int word = (n0 + wv * 32 + t * 16) >> 6;
            unsigned long long wm = bb[g * 32 + word];
            float pv[4];
#pragma unroll
            for (int r = 0; r < 4; ++r) {
                int n = nb + r;
                float l = acc[t][r];
                float e2 = __expf(2.0f * l);
                float th = 1.0f - 2.0f / (e2 + 1.0f);
                float p = ((wm >> (n & 63)) & 1ull) ? __expf(10.0f * th) : 0.0f;
                pv[r] = p;
                psum += p;
            }
            if (nb + 3 < NN) {
                *(float4*)(out + ((size_t)b * 128 + g) * NN + nb) =
                    make_float4(pv[0], pv[1], pv[2], pv[3]);
            }
        }
        psum += __shfl_xor(psum, 16);
        psum += __shfl_xor(psum, 32);
        if (q3 == 0) Zp[((size_t)(nt * 4 + wv)) * 8192 + b * 128 + g] = psum;
    }
}

// ---- K10: normalize probs (64 partial-sum slots) ----
__global__ __launch_bounds__(256) void k_norm(const float* Zp, float* out) {
    int bg = blockIdx.x;
    __shared__ float invs;
    if (threadIdx.x == 0) {
        float s = 0.0f;
#pragma unroll
        for (int t = 0; t < 64; ++t) s += Zp[(size_t)t * 8192 + bg];
        invs = 1.0f / s;
    }
    __syncthreads();
    float inv = invs;
    for (int n = threadIdx.x; n < NN; n += 256) out[(size_t)bg * NN + n] *= inv;
}

extern "C" void kernel_launch(void* const* d_in, const int* in_sizes, int n_in,
                              void* d_out, int out_size, void* d_ws, size_t ws_size,
                              hipStream_t stream) {
    const float* emb = (const float*)d_in[0];
    const float* mask = (const float*)d_in[1];
    const float* Wqg = (const float*)d_in[2];
    const float* Wqs = (const float*)d_in[3];
    const float* Wqt = (const float*)d_in[4];
    const float* Wql = (const float*)d_in[5];
    const float* Wk = (const float*)d_in[6];
    const float* Wv = (const float*)d_in[7];
    const float* Wc = (const float*)d_in[8];
    const float* bc = (const float*)d_in[9];
    const int* srcn = (const int*)d_in[10];
    const int* tgtn = (const int*)d_in[11];
    const int* lastn = (const int*)d_in[12];
    float* out = (float*)d_out;

    // ---- workspace map (float offsets); K/V = 8,192,000 floats EACH ----
    float* ws = (float*)d_ws;
    float* WT = ws;                                   // [0, 114688)
    unsigned short* Wkhi = (unsigned short*)(WT + 4 * 16384);
    unsigned short* Wklo = Wkhi + 16384;
    unsigned short* Wvhi = Wklo + 16384;
    unsigned short* Wvlo = Wvhi + 16384;
    float* gpart = ws + 114688;                       // [114688, 245760)
    float* qbase = ws + 245760;                       // [245760, 253952)
    float* MHt = ws + 253952;                         // [253952, 1302528)
    unsigned short* FQhi = (unsigned short*)(ws + 1302528);     // [1302528, 2351104)
    unsigned short* FQlo = FQhi + 1048576;
    float* Zp = ws + 2351104;                         // [2351104, 3399680)
    unsigned short* Khi = (unsigned short*)(ws + 3399680);      // [3399680, 11591680)
    unsigned short* Klo = (unsigned short*)(ws + 11591680);     // [11591680, 19783680)
    unsigned short* Vhi = (unsigned short*)(ws + 19783680);     // [19783680, 27975680)
    unsigned short* Vlo = (unsigned short*)(ws + 27975680);     // [27975680, 36167680)
    unsigned long long* bits = (unsigned long long*)(ws + 36167680);  // [36167680, 36691968)

    // flash partials + Q live in d_out (all consumed before k_logits writes it)
    float* Opart = out;                               // [0, 4194304)
    float* Zpart = out + 4194304;                     // [4194304, 4456448)
    unsigned short* Qhi = (unsigned short*)(out + 4456448);     // [4456448, 4980736)
    unsigned short* Qlo = Qhi + 1048576;                        // [4980736, 5505024)

    k_wt<<<7, 256, 0, stream>>>(Wqg, Wqs, Wqt, Wql, Wk, Wv, Wc, WT, Wkhi, Wklo, Wvhi, Wvlo);
    k_maskbits<<<8192, 256, 0, stream>>>(mask, bits);
    k_gsum<<<dim3(16, 64), 128, 0, stream>>>(emb, gpart);
    k_kv<<<dim3(16, 64), 256, 0, stream>>>(emb, Wkhi, Wklo, Wvhi, Wvlo, Khi, Klo, Vhi, Vlo);
    k_qbase<<<64, 128, 0, stream>>>(emb, srcn, tgtn, gpart, WT, qbase);
    k_qlast<<<64, 256, 0, stream>>>(emb, lastn, WT, qbase, Qhi, Qlo);
    k_flash<<<2048, 256, 0, stream>>>(Khi, Klo, Vhi, Vlo, Qhi, Qlo, bits, Opart, Zpart);
    k_ocomb<<<512, 256, 0, stream>>>(Opart, Zpart, MHt);
    k_fq<<<64, 256, 0, stream>>>(MHt, WT, bc, FQhi, FQlo);
    k_logits<<<dim3(16, 64), 256, 0, stream>>>(emb, FQhi, FQlo, bits, out, Zp);
    k_norm<<<8192, 256, 0, stream>>>(Zp, out);
}

// Round 13
// 381.540 us; speedup vs baseline: 1.7758x; 1.7758x over previous
//
#include <hip/hip_runtime.h>
#include <hip/hip_bf16.h>

#define BB 64
#define NN 2000
#define GG 128
#define HH 128
#define NHEAD 8
#define HD 16

typedef __attribute__((ext_vector_type(8))) short short8;
typedef __attribute__((ext_vector_type(4))) float f32x4;

__device__ __forceinline__ unsigned short bf16hi(float f) {
    union { float f; unsigned u; } v; v.f = f;
    return (unsigned short)(v.u >> 16);
}
__device__ __forceinline__ float bf16tof(unsigned short h) {
    union { float f; unsigned u; } v; v.u = ((unsigned)h) << 16;
    return v.f;
}

// convert 8 fp32 (two float4) -> bf16 hi/lo short8 pair
__device__ __forceinline__ void cvt8(const float4& v0, const float4& v1,
                                     short8& hi, short8& lo) {
    float fv[8] = {v0.x, v0.y, v0.z, v0.w, v1.x, v1.y, v1.z, v1.w};
#pragma unroll
    for (int i = 0; i < 8; ++i) {
        unsigned short h = bf16hi(fv[i]);
        hi[i] = (short)h;
        lo[i] = (short)bf16hi(fv[i] - bf16tof(h));
    }
}

__device__ __forceinline__ void fma8x8(const float4& a0, const float4& a1,
                                       const float4& b0, const float4& b1,
                                       float acc[8][8]) {
    const float av[8] = {a0.x, a0.y, a0.z, a0.w, a1.x, a1.y, a1.z, a1.w};
    const float bv[8] = {b0.x, b0.y, b0.z, b0.w, b1.x, b1.y, b1.z, b1.w};
#pragma unroll
    for (int i = 0; i < 8; ++i)
#pragma unroll
        for (int k = 0; k < 8; ++k) acc[i][k] += av[i] * bv[k];
}

// ---- K1: transpose Wqg,Wqs,Wqt,Wql,Wc (fp32) + convert Wk,Wv to bf16 hi/lo ----
__global__ __launch_bounds__(256) void k_wt(const float* w0, const float* w1, const float* w2,
                     const float* w3, const float* w4, const float* w5,
                     const float* w6, float* WT,
                     unsigned short* Wkhi, unsigned short* Wklo,
                     unsigned short* Wvhi, unsigned short* Wvlo) {
    int m = blockIdx.x;
    if (m >= 5) {
        const float* src = (m == 5) ? w4 : w5;
        unsigned short* dh = (m == 5) ? Wkhi : Wvhi;
        unsigned short* dl = (m == 5) ? Wklo : Wvlo;
        for (int e = threadIdx.x * 4; e < 16384; e += 1024) {
            float4 v = *(const float4*)(src + e);
            float fv[4] = {v.x, v.y, v.z, v.w};
            unsigned short h4[4], l4[4];
#pragma unroll
            for (int i = 0; i < 4; ++i) {
                h4[i] = bf16hi(fv[i]); l4[i] = bf16hi(fv[i] - bf16tof(h4[i]));
            }
            uint2 ph, pl;
            ph.x = h4[0] | (h4[1] << 16); ph.y = h4[2] | (h4[3] << 16);
            pl.x = l4[0] | (l4[1] << 16); pl.y = l4[2] | (l4[3] << 16);
            *(uint2*)(dh + e) = ph;
            *(uint2*)(dl + e) = pl;
        }
        return;
    }
    __shared__ float t[128 * 129];
    const float* src = (m == 0) ? w0 : (m == 1) ? w1 : (m == 2) ? w2 : (m == 3) ? w3 : w6;
    int slot = (m == 4) ? 6 : m;
    for (int e = threadIdx.x; e < 16384; e += 256) {
        int c = e >> 7, j = e & 127;
        t[c * 129 + j] = src[e];
    }
    __syncthreads();
    for (int e = threadIdx.x; e < 16384; e += 256) {
        int j = e >> 7, c = e & 127;
        WT[slot * 16384 + e] = t[c * 129 + j];
    }
}

// ---- K2: mask -> bitmask ----
__global__ __launch_bounds__(256) void k_maskbits(const float* mask, unsigned long long* bits) {
    int bg = blockIdx.x;
    int lane = threadIdx.x & 63;
    int wv = threadIdx.x >> 6;
    for (int w = wv; w < 32; w += 4) {
        int n = w * 64 + lane;
        bool keep = false;
        if (n < NN) keep = (mask[(size_t)bg * NN + n] == 0.0f);
        unsigned long long bal = __ballot(keep);
        if (lane == 0) bits[bg * 32 + w] = bal;
    }
}

// ---- K3: partial column sums of embeddings ----
__global__ __launch_bounds__(128) void k_gsum(const float* emb, float* gpart) {
    int ck = blockIdx.x, b = blockIdx.y, c = threadIdx.x;
    const float* p = emb + ((size_t)b * NN + ck * 125) * HH + c;
    float s = 0.0f;
#pragma unroll 5
    for (int r = 0; r < 125; ++r) s += p[(size_t)r * HH];
    gpart[ck * 8192 + b * 128 + c] = s;
}

// ---- K4: qbase ----
__global__ __launch_bounds__(128) void k_qbase(const float* emb, const int* srcn, const int* tgtn,
                        const float* gpart, const float* WT, float* qbase) {
    int b = blockIdx.x, c = threadIdx.x;
    __shared__ float ge[128], se[128], te[128];
    float s = 0.0f;
#pragma unroll
    for (int t = 0; t < 16; ++t) s += gpart[t * 8192 + b * 128 + c];
    ge[c] = s * (1.0f / 2000.0f);
    se[c] = emb[((size_t)b * NN + srcn[b]) * HH + c];
    te[c] = emb[((size_t)b * NN + tgtn[b]) * HH + c];
    __syncthreads();
    const float* Wg = WT;
    const float* Ws = WT + 16384;
    const float* Wt2 = WT + 32768;
    float acc = 0.0f;
#pragma unroll 4
    for (int j = 0; j < 128; ++j) {
        acc += ge[j] * Wg[j * 128 + c] + se[j] * Ws[j * 128 + c] + te[j] * Wt2[j * 128 + c];
    }
    qbase[b * 128 + c] = acc;
}

// ---- K5: Qhl[b][g][128] (bf16 hi/lo) = 0.25*(qbase + lastemb@WqlT) ----
__global__ __launch_bounds__(256) void k_qlast(const float* emb, const int* lastn, const float* WT,
                        const float* qbase, unsigned short* Qhi, unsigned short* Qlo) {
    int b = blockIdx.x;
    int tid = threadIdx.x, xq = tid & 15, yq = tid >> 4;
    __shared__ float Bl[128 * 132];
    for (int e = tid; e < 16384; e += 256) {
        int g = e >> 7, j = e & 127;
        Bl[j * 132 + g] = emb[((size_t)b * NN + lastn[b * 128 + g]) * HH + j];
    }
    __syncthreads();
    const float* Wql = WT + 3 * 16384;
    float acc[8][8] = {};
#pragma unroll 4
    for (int j = 0; j < 128; ++j) {
        const float4* Ar = (const float4*)(Wql + j * 128);
        float4 a0 = Ar[yq], a1 = Ar[16 + yq];
        const float4* Br = (const float4*)(Bl + j * 132);
        float4 b0 = Br[xq], b1 = Br[16 + xq];
        fma8x8(a0, a1, b0, b1, acc);
    }
    float4 qb0 = *(const float4*)(qbase + b * 128 + 4 * yq);
    float4 qb1 = *(const float4*)(qbase + b * 128 + 64 + 4 * yq);
    const float q0v[4] = {qb0.x, qb0.y, qb0.z, qb0.w};
    const float q1v[4] = {qb1.x, qb1.y, qb1.z, qb1.w};
#pragma unroll
    for (int k = 0; k < 8; ++k) {
        int g = (k < 4) ? (4 * xq + k) : (64 + 4 * xq + (k - 4));
        size_t base = ((size_t)b * 128 + g) * 128;
        unsigned short h4[4], l4[4];
#pragma unroll
        for (int i = 0; i < 4; ++i) {
            float f = (acc[i][k] + q0v[i]) * 0.25f;
            h4[i] = bf16hi(f); l4[i] = bf16hi(f - bf16tof(h4[i]));
        }
        uint2 ph, pl;
        ph.x = h4[0] | (h4[1] << 16); ph.y = h4[2] | (h4[3] << 16);
        pl.x = l4[0] | (l4[1] << 16); pl.y = l4[2] | (l4[3] << 16);
        *(uint2*)(Qhi + base + 4 * yq) = ph;
        *(uint2*)(Qlo + base + 4 * yq) = pl;
#pragma unroll
        for (int i = 0; i < 4; ++i) {
            float f = (acc[4 + i][k] + q1v[i]) * 0.25f;
            h4[i] = bf16hi(f); l4[i] = bf16hi(f - bf16tof(h4[i]));
        }
        ph.x = h4[0] | (h4[1] << 16); ph.y = h4[2] | (h4[3] << 16);
        pl.x = l4[0] | (l4[1] << 16); pl.y = l4[2] | (l4[3] << 16);
        *(uint2*)(Qhi + base + 64 + 4 * yq) = ph;
        *(uint2*)(Qlo + base + 64 + 4 * yq) = pl;
    }
}

// ---- K6: K/V projections via split-bf16 MFMA; 128-n tile, no LDS, no barriers ----
__global__ __launch_bounds__(256, 4) void k_kv(const float* emb,
        const unsigned short* Wkhi, const unsigned short* Wklo,
        const unsigned short* Wvhi, const unsigned short* Wvlo,
        unsigned short* Khi, unsigned short* Klo,
        unsigned short* Vhi, unsigned short* Vlo) {
    int nt = blockIdx.x, b = blockIdx.y;  // nt in [0,16)
    int tid = threadIdx.x;
    int wv = tid >> 6, lane = tid & 63, l15 = lane & 15, q3 = lane >> 4;
    int n0 = nt * 128;

    short8 eh[2][4], el[2][4];
#pragma unroll
    for (int t = 0; t < 2; ++t) {
        int n = n0 + wv * 32 + t * 16 + l15;
        const float* rowp = emb + ((size_t)b * NN + n) * HH + q3 * 8;
        bool ok = (n < NN);
#pragma unroll
        for (int ks = 0; ks < 4; ++ks) {
            float4 v0 = make_float4(0.f, 0.f, 0.f, 0.f), v1 = v0;
            if (ok) {
                v0 = *(const float4*)(rowp + ks * 32);
                v1 = *(const float4*)(rowp + ks * 32 + 4);
            }
            cvt8(v0, v1, eh[t][ks], el[t][ks]);
        }
    }

#pragma unroll
    for (int ct = 0; ct < 8; ++ct) {
        f32x4 aK[2] = {{0.f, 0.f, 0.f, 0.f}, {0.f, 0.f, 0.f, 0.f}};
        f32x4 aV[2] = {{0.f, 0.f, 0.f, 0.f}, {0.f, 0.f, 0.f, 0.f}};
#pragma unroll
        for (int ks = 0; ks < 4; ++ks) {
            size_t woff = ((size_t)(ct * 16 + l15)) * 128 + ks * 32 + q3 * 8;
            short8 wkh = *(const short8*)(Wkhi + woff);
            short8 wkl = *(const short8*)(Wklo + woff);
            short8 wvh = *(const short8*)(Wvhi + woff);
            short8 wvl = *(const short8*)(Wvlo + woff);
#pragma unroll
            for (int t = 0; t < 2; ++t) {
                aK[t] = __builtin_amdgcn_mfma_f32_16x16x32_bf16(wkh, eh[t][ks], aK[t], 0, 0, 0);
                aK[t] = __builtin_amdgcn_mfma_f32_16x16x32_bf16(wkh, el[t][ks], aK[t], 0, 0, 0);
                aK[t] = __builtin_amdgcn_mfma_f32_16x16x32_bf16(wkl, eh[t][ks], aK[t], 0, 0, 0);
                aV[t] = __builtin_amdgcn_mfma_f32_16x16x32_bf16(eh[t][ks], wvh, aV[t], 0, 0, 0);
                aV[t] = __builtin_amdgcn_mfma_f32_16x16x32_bf16(el[t][ks], wvh, aV[t], 0, 0, 0);
                aV[t] = __builtin_amdgcn_mfma_f32_16x16x32_bf16(eh[t][ks], wvl, aV[t], 0, 0, 0);
            }
        }
#pragma unroll
        for (int t = 0; t < 2; ++t) {
            int kn = n0 + wv * 32 + t * 16 + l15;
            if (kn < NN) {
                unsigned short h4[4], l4[4];
#pragma unroll
                for (int r = 0; r < 4; ++r) {
                    float f = aK[t][r];
                    h4[r] = bf16hi(f); l4[r] = bf16hi(f - bf16tof(h4[r]));
                }
                uint2 ph, pl;
                ph.x = h4[0] | (h4[1] << 16); ph.y = h4[2] | (h4[3] << 16);
                pl.x = l4[0] | (l4[1] << 16); pl.y = l4[2] | (l4[3] << 16);
                size_t kbase = (((size_t)b * 8 + ct) * 2000 + kn) * 16 + 4 * q3;
                *(uint2*)(Khi + kbase) = ph;
                *(uint2*)(Klo + kbase) = pl;
            }
            int nb = n0 + wv * 32 + t * 16 + 4 * q3;
            if (nb + 3 < NN) {
                unsigned short h4[4], l4[4];
#pragma unroll
                for (int r = 0; r < 4; ++r) {
                    float f = aV[t][r];
                    h4[r] = bf16hi(f); l4[r] = bf16hi(f - bf16tof(h4[r]));
                }
                uint2 ph, pl;
                ph.x = h4[0] | (h4[1] << 16); ph.y = h4[2] | (h4[3] << 16);
                pl.x = l4[0] | (l4[1] << 16); pl.y = l4[2] | (l4[3] << 16);
                size_t vbase = (((size_t)b * 8 + ct) * 16 + l15) * 2000 + nb;
                *(uint2*)(Vhi + vbase) = ph;
                *(uint2*)(Vlo + vbase) = pl;
            }
        }
    }
}

// ---- K7: MFMA flash attention; direct global K/V loads, per-wave swizzled Plds,
// ZERO barriers (in-wave LDS ordering via lgkmcnt). Out-of-range K/V zeroed (NaN guard).
__global__ __launch_bounds__(256) void k_flash(const unsigned short* Khi, const unsigned short* Klo,
                        const unsigned short* Vhi, const unsigned short* Vlo,
                        const unsigned short* Qhi, const unsigned short* Qlo,
                        const unsigned long long* bits, float* Opart, float* Zpart) {
    int bid = blockIdx.x;
    int s4 = bid & 3, h = (bid >> 2) & 7, b = bid >> 5;
    int tid = threadIdx.x;
    int wv = tid >> 6, lane = tid & 63, l15 = lane & 15, q3 = lane >> 4;

    __shared__ unsigned short Plds[4][2][32][64];  // 32 KB -> 5 blocks/CU

    const short8 z8 = {0, 0, 0, 0, 0, 0, 0, 0};

    short8 qf[2][2];
#pragma unroll
    for (int gt = 0; gt < 2; ++gt) {
        int g = wv * 32 + gt * 16 + l15;
        if (q3 < 2) {
            size_t off = ((size_t)b * 128 + g) * 128 + h * 16 + q3 * 8;
            qf[gt][0] = *(const short8*)(Qhi + off);
            qf[gt][1] = *(const short8*)(Qlo + off);
        } else {
            qf[gt][0] = z8; qf[gt][1] = z8;
        }
    }

    f32x4 Oacc[2] = {{0.f, 0.f, 0.f, 0.f}, {0.f, 0.f, 0.f, 0.f}};
    float zacc[2] = {0.f, 0.f};

    const unsigned long long* bb0 = bits + (((size_t)b * 128 + wv * 32 + l15) * 32);
    const unsigned long long* bb1 = bb0 + 16 * 32;

    size_t kvbase = ((size_t)b * 8 + h);
    const unsigned short* Kh = Khi + kvbase * 32000;
    const unsigned short* Kl = Klo + kvbase * 32000;
    const unsigned short* Vh = Vhi + kvbase * 32000;
    const unsigned short* Vl = Vlo + kvbase * 32000;

    int swz = (l15 & 7) << 3;  // 16B-granule XOR swizzle (u16 units)

    for (int ch = s4 * 8; ch < s4 * 8 + 8; ++ch) {
        int n0 = ch * 64;
        unsigned long long wm0 = bb0[ch];
        unsigned long long wm1 = bb1[ch];

        // --- QK^T + mask/exp + pack into swizzled per-wave Plds ---
#pragma unroll
        for (int nt = 0; nt < 4; ++nt) {
            short8 kh = z8, kl = z8;
            int kn = n0 + nt * 16 + l15;
            if (q3 < 2 && kn < NN) {
                size_t koff = ((size_t)kn) * 16 + q3 * 8;
                kh = *(const short8*)(Kh + koff);
                kl = *(const short8*)(Kl + koff);
            }
            int colw = (nt * 16 + q3 * 4) ^ swz;
#pragma unroll
            for (int gt = 0; gt < 2; ++gt) {
                f32x4 c = {0.f, 0.f, 0.f, 0.f};
                c = __builtin_amdgcn_mfma_f32_16x16x32_bf16(kh, qf[gt][0], c, 0, 0, 0);
                c = __builtin_amdgcn_mfma_f32_16x16x32_bf16(kh, qf[gt][1], c, 0, 0, 0);
                c = __builtin_amdgcn_mfma_f32_16x16x32_bf16(kl, qf[gt][0], c, 0, 0, 0);
                unsigned long long wm = gt ? wm1 : wm0;
                float p[4];
#pragma unroll
                for (int r = 0; r < 4; ++r) {
                    int sh = nt * 16 + q3 * 4 + r;
                    float e = ((wm >> sh) & 1ull) ? __expf(c[r]) : 0.0f;
                    p[r] = e;
                    zacc[gt] += e;
                }
                unsigned short h4[4], l4[4];
#pragma unroll
                for (int r = 0; r < 4; ++r) {
                    h4[r] = bf16hi(p[r]); l4[r] = bf16hi(p[r] - bf16tof(h4[r]));
                }
                uint2 ph, pl;
                ph.x = (unsigned)h4[0] | ((unsigned)h4[1] << 16); ph.y = (unsigned)h4[2] | ((unsigned)h4[3] << 16);
                pl.x = (unsigned)l4[0] | ((unsigned)l4[1] << 16); pl.y = (unsigned)l4[2] | ((unsigned)l4[3] << 16);
                *(uint2*)&Plds[wv][0][gt * 16 + l15][colw] = ph;
                *(uint2*)&Plds[wv][1][gt * 16 + l15][colw] = pl;
            }
        }

        // --- PV: V direct from global, P from swizzled Plds (same wave, no barrier) ---
#pragma unroll
        for (int ks = 0; ks < 2; ++ks) {
            short8 vh = z8, vl = z8;
            int vn = n0 + ks * 32 + q3 * 8;  // 8-aligned; NN=2000 divisible by 8
            if (vn < NN) {
                size_t voff = (size_t)l15 * 2000 + vn;
                vh = *(const short8*)(Vh + voff);
                vl = *(const short8*)(Vl + voff);
            }
            int colr = (ks * 32 + q3 * 8) ^ swz;
#pragma unroll
            for (int gt = 0; gt < 2; ++gt) {
                short8 ph = *(const short8*)&Plds[wv][0][gt * 16 + l15][colr];
                short8 pl = *(const short8*)&Plds[wv][1][gt * 16 + l15][colr];
                Oacc[gt] = __builtin_amdgcn_mfma_f32_16x16x32_bf16(vh, ph, Oacc[gt], 0, 0, 0);
                Oacc[gt] = __builtin_amdgcn_mfma_f32_16x16x32_bf16(vh, pl, Oacc[gt], 0, 0, 0);
                Oacc[gt] = __builtin_amdgcn_mfma_f32_16x16x32_bf16(vl, ph, Oacc[gt], 0, 0, 0);
            }
        }
    }

    size_t obase = (((size_t)s4 * 64 + b) * 8 + h);
#pragma unroll
    for (int gt = 0; gt < 2; ++gt) {
        float z = zacc[gt];
        z += __shfl_xor(z, 16);
        z += __shfl_xor(z, 32);
        int g = wv * 32 + gt * 16 + l15;
        if (q3 == 0) Zpart[obase * 128 + g] = z;
#pragma unroll
        for (int r = 0; r < 4; ++r) {
            int d = q3 * 4 + r;
            Opart[(obase * 16 + d) * 128 + g] = Oacc[gt][r];
        }
    }
}

// ---- K7b: combine partials -> MHt[b][h*16+d][g] ----
__global__ __launch_bounds__(256) void k_ocomb(const float* Opart, const float* Zpart, float* MHt) {
    int bh = blockIdx.x;
    int b = bh >> 3, h = bh & 7;
    int tid = threadIdx.x;
    for (int e = tid; e < 2048; e += 256) {
        int d = e >> 7, g = e & 127;
        float z = 0.0f, o = 0.0f;
#pragma unroll
        for (int s = 0; s < 4; ++s) {
            z += Zpart[(((size_t)s * 64 + b) * 8 + h) * 128 + g];
            o += Opart[((((size_t)s * 64 + b) * 8 + h) * 16 + d) * 128 + g];
        }
        MHt[((size_t)b * 128 + h * 16 + d) * 128 + g] = o / z;
    }
}

// ---- K8: FQhl[b][g][c] (bf16 hi/lo) = (MH[b][g]@WcT + bc)*rsqrt(H) ----
__global__ __launch_bounds__(256) void k_fq(const float* MHt, const float* WT, const float* bcv,
                                            unsigned short* FQhi, unsigned short* FQlo) {
    int b = blockIdx.x;
    int tid = threadIdx.x, xq = tid & 15, yq = tid >> 4;
    __shared__ float Bl[128 * 132];
    for (int e = tid; e < 16384; e += 256) {
        int j = e >> 7, g = e & 127;
        Bl[j * 132 + g] = MHt[(size_t)b * 16384 + e];
    }
    __syncthreads();
    const float* Wc = WT + 6 * 16384;
    float acc[8][8] = {};
#pragma unroll 4
    for (int j = 0; j < 128; ++j) {
        const float4* Ar = (const float4*)(Wc + j * 128);
        float4 a0 = Ar[yq], a1 = Ar[16 + yq];
        const float4* Br = (const float4*)(Bl + j * 132);
        float4 b0 = Br[xq], b1 = Br[16 + xq];
        fma8x8(a0, a1, b0, b1, acc);
    }
    float4 bc0 = *(const float4*)(bcv + 4 * yq);
    float4 bc1 = *(const float4*)(bcv + 64 + 4 * yq);
    const float bcv8[8] = {bc0.x, bc0.y, bc0.z, bc0.w, bc1.x, bc1.y, bc1.z, bc1.w};
    const float sc = 0.08838834764831845f;  // 1/sqrt(128)
#pragma unroll
    for (int k = 0; k < 8; ++k) {
        int g = (k < 4) ? (4 * xq + k) : (64 + 4 * xq + (k - 4));
        size_t base = ((size_t)b * 128 + g) * 128;
        unsigned short h4[4], l4[4];
#pragma unroll
        for (int i = 0; i < 4; ++i) {
            float f = (acc[i][k] + bcv8[i]) * sc;
            h4[i] = bf16hi(f); l4[i] = bf16hi(f - bf16tof(h4[i]));
        }
        uint2 ph, pl;
        ph.x = h4[0] | (h4[1] << 16); ph.y = h4[2] | (h4[3] << 16);
        pl.x = l4[0] | (l4[1] << 16); pl.y = l4[2] | (l4[3] << 16);
        *(uint2*)(FQhi + base + 4 * yq) = ph;
        *(uint2*)(FQlo + base + 4 * yq) = pl;
#pragma unroll
        for (int i = 0; i < 4; ++i) {
            float f = (acc[4 + i][k] + bcv8[4 + i]) * sc;
            h4[i] = bf16hi(f); l4[i] = bf16hi(f - bf16tof(h4[i]));
        }
        ph.x = h4[0] | (h4[1] << 16); ph.y = h4[2] | (h4[3] << 16);
        pl.x = l4[0] | (l4[1] << 16); pl.y = l4[2] | (l4[3] << 16);
        *(uint2*)(FQhi + base + 64 + 4 * yq) = ph;
        *(uint2*)(FQlo + base + 64 + 4 * yq) = pl;
    }
}

// ---- K9: logits via split-bf16 MFMA; swapped operands; no LDS, no barriers ----
__global__ __launch_bounds__(256, 4) void k_logits(const float* emb,
        const unsigned short* FQhi, const unsigned short* FQlo,
        const unsigned long long* bits, float* out, float* Zp) {
    int nt = blockIdx.x, b = blockIdx.y;  // nt in [0,16)
    int tid = threadIdx.x;
    int wv = tid >> 6, lane = tid & 63, l15 = lane & 15, q3 = lane >> 4;
    int n0 = nt * 128;

    short8 beh[2][4], bel[2][4];
#pragma unroll
    for (int t = 0; t < 2; ++t) {
        int n = n0 + wv * 32 + t * 16 + l15;
        const float* rowp = emb + ((size_t)b * NN + n) * HH + q3 * 8;
        bool ok = (n < NN);
#pragma unroll
        for (int ks = 0; ks < 4; ++ks) {
            float4 v0 = make_float4(0.f, 0.f, 0.f, 0.f), v1 = v0;
            if (ok) {
                v0 = *(const float4*)(rowp + ks * 32);
                v1 = *(const float4*)(rowp + ks * 32 + 4);
            }
            cvt8(v0, v1, beh[t][ks], bel[t][ks]);
        }
    }

    const unsigned long long* bb = bits + (size_t)b * 128 * 32;
    int g = 0;
#pragma unroll
    for (int gt = 0; gt < 8; ++gt) {
        f32x4 acc[2] = {{0.f, 0.f, 0.f, 0.f}, {0.f, 0.f, 0.f, 0.f}};
#pragma unroll
        for (int ks = 0; ks < 4; ++ks) {
            size_t foff = ((size_t)b * 128 + gt * 16 + l15) * 128 + ks * 32 + q3 * 8;
            short8 fh = *(const short8*)(FQhi + foff);
            short8 fl = *(const short8*)(FQlo + foff);
#pragma unroll
            for (int t = 0; t < 2; ++t) {
                acc[t] = __builtin_amdgcn_mfma_f32_16x16x32_bf16(beh[t][ks], fh, acc[t], 0, 0, 0);
                acc[t] = __builtin_amdgcn_mfma_f32_16x16x32_bf16(bel[t][ks], fh, acc[t], 0, 0, 0);
                acc[t] = __builtin_amdgcn_mfma_f32_16x16x32_bf16(beh[t][ks], fl, acc[t], 0, 0, 0);
            }
        }
        g = gt * 16 + l15;
        float psum = 0.f;
#pragma unroll
        for (int t = 0; t < 2; ++t) {
            int nb = n0 + wv * 32 + t * 16 + 4 * q3;
            int word = (n0 + wv * 32 + t * 16) >> 6;
            unsigned long long wm = bb[g * 32 + word];
            float pv[4];
#pragma unroll
            for (int r = 0; r < 4; ++r) {
                int n = nb + r;
                float l = acc[t][r];
                float e2 = __expf(2.0f * l);
                float th = 1.0f - 2.0f / (e2 + 1.0f);
                float p = ((wm >> (n & 63)) & 1ull) ? __expf(10.0f * th) : 0.0f;
                pv[r] = p;
                psum += p;
            }
            if (nb + 3 < NN) {
                *(float4*)(out + ((size_t)b * 128 + g) * NN + nb) =
                    make_float4(pv[0], pv[1], pv[2], pv[3]);
            }
        }
        psum += __shfl_xor(psum, 16);
        psum += __shfl_xor(psum, 32);
        if (q3 == 0) Zp[((size_t)(nt * 4 + wv)) * 8192 + b * 128 + g] = psum;
    }
}

// ---- K10: normalize probs (64 partial-sum slots) ----
__global__ __launch_bounds__(256) void k_norm(const float* Zp, float* out) {
    int bg = blockIdx.x;
    __shared__ float invs;
    if (threadIdx.x == 0) {
        float s = 0.0f;
#pragma unroll
        for (int t = 0; t < 64; ++t) s += Zp[(size_t)t * 8192 + bg];
        invs = 1.0f / s;
    }
    __syncthreads();
    float inv = invs;
    for (int n = threadIdx.x; n < NN; n += 256) out[(size_t)bg * NN + n] *= inv;
}

extern "C" void kernel_launch(void* const* d_in, const int* in_sizes, int n_in,
                              void* d_out, int out_size, void* d_ws, size_t ws_size,
                              hipStream_t stream) {
    const float* emb = (const float*)d_in[0];
    const float* mask = (const float*)d_in[1];
    const float* Wqg = (const float*)d_in[2];
    const float* Wqs = (const float*)d_in[3];
    const float* Wqt = (const float*)d_in[4];
    const float* Wql = (const float*)d_in[5];
    const float* Wk = (const float*)d_in[6];
    const float* Wv = (const float*)d_in[7];
    const float* Wc = (const float*)d_in[8];
    const float* bc = (const float*)d_in[9];
    const int* srcn = (const int*)d_in[10];
    const int* tgtn = (const int*)d_in[11];
    const int* lastn = (const int*)d_in[12];
    float* out = (float*)d_out;

    // ---- workspace map (float offsets); K/V = 8,192,000 floats EACH ----
    float* ws = (float*)d_ws;
    float* WT = ws;                                   // [0, 114688)
    unsigned short* Wkhi = (unsigned short*)(WT + 4 * 16384);
    unsigned short* Wklo = Wkhi + 16384;
    unsigned short* Wvhi = Wklo + 16384;
    unsigned short* Wvlo = Wvhi + 16384;
    float* gpart = ws + 114688;                       // [114688, 245760)
    float* qbase = ws + 245760;                       // [245760, 253952)
    float* MHt = ws + 253952;                         // [253952, 1302528)
    unsigned short* FQhi = (unsigned short*)(ws + 1302528);     // [1302528, 2351104)
    unsigned short* FQlo = FQhi + 1048576;
    float* Zp = ws + 2351104;                         // [2351104, 3399680)
    unsigned short* Khi = (unsigned short*)(ws + 3399680);      // [3399680, 11591680)
    unsigned short* Klo = (unsigned short*)(ws + 11591680);     // [11591680, 19783680)
    unsigned short* Vhi = (unsigned short*)(ws + 19783680);     // [19783680, 27975680)
    unsigned short* Vlo = (unsigned short*)(ws + 27975680);     // [27975680, 36167680)
    unsigned long long* bits = (unsigned long long*)(ws + 36167680);  // [36167680, 36691968)

    // flash partials + Q live in d_out (all consumed before k_logits writes it)
    float* Opart = out;                               // [0, 4194304)
    float* Zpart = out + 4194304;                     // [4194304, 4456448)
    unsigned short* Qhi = (unsigned short*)(out + 4456448);     // [4456448, 4980736)
    unsigned short* Qlo = Qhi + 1048576;                        // [4980736, 5505024)

    k_wt<<<7, 256, 0, stream>>>(Wqg, Wqs, Wqt, Wql, Wk, Wv, Wc, WT, Wkhi, Wklo, Wvhi, Wvlo);
    k_maskbits<<<8192, 256, 0, stream>>>(mask, bits);
    k_gsum<<<dim3(16, 64), 128, 0, stream>>>(emb, gpart);
    k_kv<<<dim3(16, 64), 256, 0, stream>>>(emb, Wkhi, Wklo, Wvhi, Wvlo, Khi, Klo, Vhi, Vlo);
    k_qbase<<<64, 128, 0, stream>>>(emb, srcn, tgtn, gpart, WT, qbase);
    k_qlast<<<64, 256, 0, stream>>>(emb, lastn, WT, qbase, Qhi, Qlo);
    k_flash<<<2048, 256, 0, stream>>>(Khi, Klo, Vhi, Vlo, Qhi, Qlo, bits, Opart, Zpart);
    k_ocomb<<<512, 256, 0, stream>>>(Opart, Zpart, MHt);
    k_fq<<<64, 256, 0, stream>>>(MHt, WT, bc, FQhi, FQlo);
    k_logits<<<dim3(16, 64), 256, 0, stream>>>(emb, FQhi, FQlo, bits, out, Zp);
    k_norm<<<8192, 256, 0, stream>>>(Zp, out);
}

// Round 14
// 367.655 us; speedup vs baseline: 1.8429x; 1.0378x over previous
//
#include <hip/hip_runtime.h>
#include <hip/hip_bf16.h>

#define BB 64
#define NN 2000
#define GG 128
#define HH 128
#define NHEAD 8
#define HD 16

typedef __attribute__((ext_vector_type(8))) short short8;
typedef __attribute__((ext_vector_type(4))) float f32x4;

__device__ __forceinline__ unsigned short bf16hi(float f) {
    union { float f; unsigned u; } v; v.f = f;
    return (unsigned short)(v.u >> 16);
}
__device__ __forceinline__ float bf16tof(unsigned short h) {
    union { float f; unsigned u; } v; v.u = ((unsigned)h) << 16;
    return v.f;
}

// packed RNE bf16x2 conversion (v_cvt_pk_bf16_f32) + unpack helpers
__device__ __forceinline__ unsigned cvtpk_bf16(float a, float b) {
    union { __hip_bfloat162 v; unsigned u; } t;
    t.v = __float22bfloat162_rn(make_float2(a, b));
    return t.u;
}
__device__ __forceinline__ float bf16lo_f(unsigned u) {
    union { unsigned u; float f; } t; t.u = u << 16; return t.f;
}
__device__ __forceinline__ float bf16hi_f(unsigned u) {
    union { unsigned u; float f; } t; t.u = u & 0xFFFF0000u; return t.f;
}

// convert 8 fp32 (two float4) -> bf16 hi/lo short8 pair
__device__ __forceinline__ void cvt8(const float4& v0, const float4& v1,
                                     short8& hi, short8& lo) {
    float fv[8] = {v0.x, v0.y, v0.z, v0.w, v1.x, v1.y, v1.z, v1.w};
#pragma unroll
    for (int i = 0; i < 8; ++i) {
        unsigned short h = bf16hi(fv[i]);
        hi[i] = (short)h;
        lo[i] = (short)bf16hi(fv[i] - bf16tof(h));
    }
}

__device__ __forceinline__ void fma8x8(const float4& a0, const float4& a1,
                                       const float4& b0, const float4& b1,
                                       float acc[8][8]) {
    const float av[8] = {a0.x, a0.y, a0.z, a0.w, a1.x, a1.y, a1.z, a1.w};
    const float bv[8] = {b0.x, b0.y, b0.z, b0.w, b1.x, b1.y, b1.z, b1.w};
#pragma unroll
    for (int i = 0; i < 8; ++i)
#pragma unroll
        for (int k = 0; k < 8; ++k) acc[i][k] += av[i] * bv[k];
}

// ---- K1: transpose Wqg,Wqs,Wqt,Wql,Wc (fp32) + convert Wk,Wv to bf16 hi/lo ----
__global__ __launch_bounds__(256) void k_wt(const float* w0, const float* w1, const float* w2,
                     const float* w3, const float* w4, const float* w5,
                     const float* w6, float* WT,
                     unsigned short* Wkhi, unsigned short* Wklo,
                     unsigned short* Wvhi, unsigned short* Wvlo) {
    int m = blockIdx.x;
    if (m >= 5) {
        const float* src = (m == 5) ? w4 : w5;
        unsigned short* dh = (m == 5) ? Wkhi : Wvhi;
        unsigned short* dl = (m == 5) ? Wklo : Wvlo;
        for (int e = threadIdx.x * 4; e < 16384; e += 1024) {
            float4 v = *(const float4*)(src + e);
            float fv[4] = {v.x, v.y, v.z, v.w};
            unsigned short h4[4], l4[4];
#pragma unroll
            for (int i = 0; i < 4; ++i) {
                h4[i] = bf16hi(fv[i]); l4[i] = bf16hi(fv[i] - bf16tof(h4[i]));
            }
            uint2 ph, pl;
            ph.x = h4[0] | (h4[1] << 16); ph.y = h4[2] | (h4[3] << 16);
            pl.x = l4[0] | (l4[1] << 16); pl.y = l4[2] | (l4[3] << 16);
            *(uint2*)(dh + e) = ph;
            *(uint2*)(dl + e) = pl;
        }
        return;
    }
    __shared__ float t[128 * 129];
    const float* src = (m == 0) ? w0 : (m == 1) ? w1 : (m == 2) ? w2 : (m == 3) ? w3 : w6;
    int slot = (m == 4) ? 6 : m;
    for (int e = threadIdx.x; e < 16384; e += 256) {
        int c = e >> 7, j = e & 127;
        t[c * 129 + j] = src[e];
    }
    __syncthreads();
    for (int e = threadIdx.x; e < 16384; e += 256) {
        int j = e >> 7, c = e & 127;
        WT[slot * 16384 + e] = t[c * 129 + j];
    }
}

// ---- K2: mask -> bitmask ----
__global__ __launch_bounds__(256) void k_maskbits(const float* mask, unsigned long long* bits) {
    int bg = blockIdx.x;
    int lane = threadIdx.x & 63;
    int wv = threadIdx.x >> 6;
    for (int w = wv; w < 32; w += 4) {
        int n = w * 64 + lane;
        bool keep = false;
        if (n < NN) keep = (mask[(size_t)bg * NN + n] == 0.0f);
        unsigned long long bal = __ballot(keep);
        if (lane == 0) bits[bg * 32 + w] = bal;
    }
}

// ---- K3: partial column sums of embeddings ----
__global__ __launch_bounds__(128) void k_gsum(const float* emb, float* gpart) {
    int ck = blockIdx.x, b = blockIdx.y, c = threadIdx.x;
    const float* p = emb + ((size_t)b * NN + ck * 125) * HH + c;
    float s = 0.0f;
#pragma unroll 5
    for (int r = 0; r < 125; ++r) s += p[(size_t)r * HH];
    gpart[ck * 8192 + b * 128 + c] = s;
}

// ---- K4: qbase ----
__global__ __launch_bounds__(128) void k_qbase(const float* emb, const int* srcn, const int* tgtn,
                        const float* gpart, const float* WT, float* qbase) {
    int b = blockIdx.x, c = threadIdx.x;
    __shared__ float ge[128], se[128], te[128];
    float s = 0.0f;
#pragma unroll
    for (int t = 0; t < 16; ++t) s += gpart[t * 8192 + b * 128 + c];
    ge[c] = s * (1.0f / 2000.0f);
    se[c] = emb[((size_t)b * NN + srcn[b]) * HH + c];
    te[c] = emb[((size_t)b * NN + tgtn[b]) * HH + c];
    __syncthreads();
    const float* Wg = WT;
    const float* Ws = WT + 16384;
    const float* Wt2 = WT + 32768;
    float acc = 0.0f;
#pragma unroll 4
    for (int j = 0; j < 128; ++j) {
        acc += ge[j] * Wg[j * 128 + c] + se[j] * Ws[j * 128 + c] + te[j] * Wt2[j * 128 + c];
    }
    qbase[b * 128 + c] = acc;
}

// ---- K5: Qhl[b][g][128] (bf16 hi/lo) = 0.25*(qbase + lastemb@WqlT) ----
__global__ __launch_bounds__(256) void k_qlast(const float* emb, const int* lastn, const float* WT,
                        const float* qbase, unsigned short* Qhi, unsigned short* Qlo) {
    int b = blockIdx.x;
    int tid = threadIdx.x, xq = tid & 15, yq = tid >> 4;
    __shared__ float Bl[128 * 132];
    for (int e = tid; e < 16384; e += 256) {
        int g = e >> 7, j = e & 127;
        Bl[j * 132 + g] = emb[((size_t)b * NN + lastn[b * 128 + g]) * HH + j];
    }
    __syncthreads();
    const float* Wql = WT + 3 * 16384;
    float acc[8][8] = {};
#pragma unroll 4
    for (int j = 0; j < 128; ++j) {
        const float4* Ar = (const float4*)(Wql + j * 128);
        float4 a0 = Ar[yq], a1 = Ar[16 + yq];
        const float4* Br = (const float4*)(Bl + j * 132);
        float4 b0 = Br[xq], b1 = Br[16 + xq];
        fma8x8(a0, a1, b0, b1, acc);
    }
    float4 qb0 = *(const float4*)(qbase + b * 128 + 4 * yq);
    float4 qb1 = *(const float4*)(qbase + b * 128 + 64 + 4 * yq);
    const float q0v[4] = {qb0.x, qb0.y, qb0.z, qb0.w};
    const float q1v[4] = {qb1.x, qb1.y, qb1.z, qb1.w};
#pragma unroll
    for (int k = 0; k < 8; ++k) {
        int g = (k < 4) ? (4 * xq + k) : (64 + 4 * xq + (k - 4));
        size_t base = ((size_t)b * 128 + g) * 128;
        unsigned short h4[4], l4[4];
#pragma unroll
        for (int i = 0; i < 4; ++i) {
            float f = (acc[i][k] + q0v[i]) * 0.25f;
            h4[i] = bf16hi(f); l4[i] = bf16hi(f - bf16tof(h4[i]));
        }
        uint2 ph, pl;
        ph.x = h4[0] | (h4[1] << 16); ph.y = h4[2] | (h4[3] << 16);
        pl.x = l4[0] | (l4[1] << 16); pl.y = l4[2] | (l4[3] << 16);
        *(uint2*)(Qhi + base + 4 * yq) = ph;
        *(uint2*)(Qlo + base + 4 * yq) = pl;
#pragma unroll
        for (int i = 0; i < 4; ++i) {
            float f = (acc[4 + i][k] + q1v[i]) * 0.25f;
            h4[i] = bf16hi(f); l4[i] = bf16hi(f - bf16tof(h4[i]));
        }
        ph.x = h4[0] | (h4[1] << 16); ph.y = h4[2] | (h4[3] << 16);
        pl.x = l4[0] | (l4[1] << 16); pl.y = l4[2] | (l4[3] << 16);
        *(uint2*)(Qhi + base + 64 + 4 * yq) = ph;
        *(uint2*)(Qlo + base + 64 + 4 * yq) = pl;
    }
}

// ---- K6: K/V projections via split-bf16 MFMA; 128-n tile, no LDS, no barriers ----
__global__ __launch_bounds__(256, 4) void k_kv(const float* emb,
        const unsigned short* Wkhi, const unsigned short* Wklo,
        const unsigned short* Wvhi, const unsigned short* Wvlo,
        unsigned short* Khi, unsigned short* Klo,
        unsigned short* Vhi, unsigned short* Vlo) {
    int nt = blockIdx.x, b = blockIdx.y;  // nt in [0,16)
    int tid = threadIdx.x;
    int wv = tid >> 6, lane = tid & 63, l15 = lane & 15, q3 = lane >> 4;
    int n0 = nt * 128;

    short8 eh[2][4], el[2][4];
#pragma unroll
    for (int t = 0; t < 2; ++t) {
        int n = n0 + wv * 32 + t * 16 + l15;
        const float* rowp = emb + ((size_t)b * NN + n) * HH + q3 * 8;
        bool ok = (n < NN);
#pragma unroll
        for (int ks = 0; ks < 4; ++ks) {
            float4 v0 = make_float4(0.f, 0.f, 0.f, 0.f), v1 = v0;
            if (ok) {
                v0 = *(const float4*)(rowp + ks * 32);
                v1 = *(const float4*)(rowp + ks * 32 + 4);
            }
            cvt8(v0, v1, eh[t][ks], el[t][ks]);
        }
    }

#pragma unroll
    for (int ct = 0; ct < 8; ++ct) {
        f32x4 aK[2] = {{0.f, 0.f, 0.f, 0.f}, {0.f, 0.f, 0.f, 0.f}};
        f32x4 aV[2] = {{0.f, 0.f, 0.f, 0.f}, {0.f, 0.f, 0.f, 0.f}};
#pragma unroll
        for (int ks = 0; ks < 4; ++ks) {
            size_t woff = ((size_t)(ct * 16 + l15)) * 128 + ks * 32 + q3 * 8;
            short8 wkh = *(const short8*)(Wkhi + woff);
            short8 wkl = *(const short8*)(Wklo + woff);
            short8 wvh = *(const short8*)(Wvhi + woff);
            short8 wvl = *(const short8*)(Wvlo + woff);
#pragma unroll
            for (int t = 0; t < 2; ++t) {
                aK[t] = __builtin_amdgcn_mfma_f32_16x16x32_bf16(wkh, eh[t][ks], aK[t], 0, 0, 0);
                aK[t] = __builtin_amdgcn_mfma_f32_16x16x32_bf16(wkh, el[t][ks], aK[t], 0, 0, 0);
                aK[t] = __builtin_amdgcn_mfma_f32_16x16x32_bf16(wkl, eh[t][ks], aK[t], 0, 0, 0);
                aV[t] = __builtin_amdgcn_mfma_f32_16x16x32_bf16(eh[t][ks], wvh, aV[t], 0, 0, 0);
                aV[t] = __builtin_amdgcn_mfma_f32_16x16x32_bf16(el[t][ks], wvh, aV[t], 0, 0, 0);
                aV[t] = __builtin_amdgcn_mfma_f32_16x16x32_bf16(eh[t][ks], wvl, aV[t], 0, 0, 0);
            }
        }
#pragma unroll
        for (int t = 0; t < 2; ++t) {
            int kn = n0 + wv * 32 + t * 16 + l15;
            if (kn < NN) {
                unsigned short h4[4], l4[4];
#pragma unroll
                for (int r = 0; r < 4; ++r) {
                    float f = aK[t][r];
                    h4[r] = bf16hi(f); l4[r] = bf16hi(f - bf16tof(h4[r]));
                }
                uint2 ph, pl;
                ph.x = h4[0] | (h4[1] << 16); ph.y = h4[2] | (h4[3] << 16);
                pl.x = l4[0] | (l4[1] << 16); pl.y = l4[2] | (l4[3] << 16);
                size_t kbase = (((size_t)b * 8 + ct) * 2000 + kn) * 16 + 4 * q3;
                *(uint2*)(Khi + kbase) = ph;
                *(uint2*)(Klo + kbase) = pl;
            }
            int nb = n0 + wv * 32 + t * 16 + 4 * q3;
            if (nb + 3 < NN) {
                unsigned short h4[4], l4[4];
#pragma unroll
                for (int r = 0; r < 4; ++r) {
                    float f = aV[t][r];
                    h4[r] = bf16hi(f); l4[r] = bf16hi(f - bf16tof(h4[r]));
                }
                uint2 ph, pl;
                ph.x = h4[0] | (h4[1] << 16); ph.y = h4[2] | (h4[3] << 16);
                pl.x = l4[0] | (l4[1] << 16); pl.y = l4[2] | (l4[3] << 16);
                size_t vbase = (((size_t)b * 8 + ct) * 16 + l15) * 2000 + nb;
                *(uint2*)(Vhi + vbase) = ph;
                *(uint2*)(Vlo + vbase) = pl;
            }
        }
    }
}

// ---- K7: MFMA flash attention (round-10 staged structure) + cvt_pk pack + 4-bit mask ----
__global__ __launch_bounds__(256) void k_flash(const unsigned short* Khi, const unsigned short* Klo,
                        const unsigned short* Vhi, const unsigned short* Vlo,
                        const unsigned short* Qhi, const unsigned short* Qlo,
                        const unsigned long long* bits, float* Opart, float* Zpart) {
    int bid = blockIdx.x;
    int s4 = bid & 3, h = (bid >> 2) & 7, b = bid >> 5;
    int tid = threadIdx.x;
    int wv = tid >> 6, lane = tid & 63, l15 = lane & 15, q3 = lane >> 4;

    __shared__ unsigned short Klds[2][64][24];
    __shared__ unsigned short Vlds[2][16][72];
    __shared__ unsigned short Plds[4][2][32][72];

    const short8 z8 = {0, 0, 0, 0, 0, 0, 0, 0};

    short8 qf[2][2];
#pragma unroll
    for (int gt = 0; gt < 2; ++gt) {
        int g = wv * 32 + gt * 16 + l15;
        if (q3 < 2) {
            size_t off = ((size_t)b * 128 + g) * 128 + h * 16 + q3 * 8;
            qf[gt][0] = *(const short8*)(Qhi + off);
            qf[gt][1] = *(const short8*)(Qlo + off);
        } else {
            qf[gt][0] = z8; qf[gt][1] = z8;
        }
    }

    f32x4 Oacc[2] = {{0.f, 0.f, 0.f, 0.f}, {0.f, 0.f, 0.f, 0.f}};
    float zacc[2] = {0.f, 0.f};

    const unsigned long long* bb0 = bits + (((size_t)b * 128 + wv * 32 + l15) * 32);
    const unsigned long long* bb1 = bb0 + 16 * 32;

    size_t kvbase = ((size_t)b * 8 + h);
    const unsigned short* Kh = Khi + kvbase * 32000;
    const unsigned short* Kl = Klo + kvbase * 32000;
    const unsigned short* Vh = Vhi + kvbase * 32000;
    const unsigned short* Vl = Vlo + kvbase * 32000;

    int snr = tid >> 2, sj4 = (tid & 3) * 4;
    int svd = tid >> 4, svn = (tid & 15) * 4;

    for (int ch = s4 * 8; ch < s4 * 8 + 8; ++ch) {
        int n0 = ch * 64;
        __syncthreads();
        {
            uint2 zz; zz.x = 0; zz.y = 0;
            int n = n0 + snr;
            uint2 k0 = zz, k1 = zz;
            if (n < NN) {
                size_t off = ((size_t)n) * 16 + sj4;
                k0 = *(const uint2*)(Kh + off);
                k1 = *(const uint2*)(Kl + off);
            }
            *(uint2*)&Klds[0][snr][sj4] = k0;
            *(uint2*)&Klds[1][snr][sj4] = k1;
            int vn = n0 + svn;
            uint2 v0 = zz, v1 = zz;
            if (vn + 3 < NN) {
                size_t off = ((size_t)svd) * 2000 + vn;
                v0 = *(const uint2*)(Vh + off);
                v1 = *(const uint2*)(Vl + off);
            }
            *(uint2*)&Vlds[0][svd][svn] = v0;
            *(uint2*)&Vlds[1][svd][svn] = v1;
        }
        __syncthreads();

        unsigned long long wm0 = bb0[ch];
        unsigned long long wm1 = bb1[ch];

        f32x4 S[4][2];
#pragma unroll
        for (int nt = 0; nt < 4; ++nt) {
            short8 kh, kl;
            if (q3 < 2) {
                kh = *(const short8*)&Klds[0][nt * 16 + l15][q3 * 8];
                kl = *(const short8*)&Klds[1][nt * 16 + l15][q3 * 8];
            } else { kh = z8; kl = z8; }
#pragma unroll
            for (int gt = 0; gt < 2; ++gt) {
                f32x4 c = {0.f, 0.f, 0.f, 0.f};
                c = __builtin_amdgcn_mfma_f32_16x16x32_bf16(kh, qf[gt][0], c, 0, 0, 0);
                c = __builtin_amdgcn_mfma_f32_16x16x32_bf16(kh, qf[gt][1], c, 0, 0, 0);
                c = __builtin_amdgcn_mfma_f32_16x16x32_bf16(kl, qf[gt][0], c, 0, 0, 0);
                S[nt][gt] = c;
            }
        }

#pragma unroll
        for (int nt = 0; nt < 4; ++nt) {
#pragma unroll
            for (int gt = 0; gt < 2; ++gt) {
                unsigned long long wm = gt ? wm1 : wm0;
                unsigned m4 = (unsigned)(wm >> (nt * 16 + q3 * 4)) & 0xFu;
                float p[4];
#pragma unroll
                for (int r = 0; r < 4; ++r) {
                    float e = ((m4 >> r) & 1u) ? __expf(S[nt][gt][r]) : 0.0f;
                    p[r] = e;
                    zacc[gt] += e;
                }
                unsigned hp0 = cvtpk_bf16(p[0], p[1]);
                unsigned hp1 = cvtpk_bf16(p[2], p[3]);
                float l0 = p[0] - bf16lo_f(hp0);
                float l1 = p[1] - bf16hi_f(hp0);
                float l2 = p[2] - bf16lo_f(hp1);
                float l3 = p[3] - bf16hi_f(hp1);
                unsigned lp0 = cvtpk_bf16(l0, l1);
                unsigned lp1 = cvtpk_bf16(l2, l3);
                uint2 ph, pl;
                ph.x = hp0; ph.y = hp1;
                pl.x = lp0; pl.y = lp1;
                *(uint2*)&Plds[wv][0][gt * 16 + l15][nt * 16 + q3 * 4] = ph;
                *(uint2*)&Plds[wv][1][gt * 16 + l15][nt * 16 + q3 * 4] = pl;
            }
        }

#pragma unroll
        for (int ks = 0; ks < 2; ++ks) {
            short8 vh = *(const short8*)&Vlds[0][l15][ks * 32 + q3 * 8];
            short8 vl = *(const short8*)&Vlds[1][l15][ks * 32 + q3 * 8];
#pragma unroll
            for (int gt = 0; gt < 2; ++gt) {
                short8 ph = *(const short8*)&Plds[wv][0][gt * 16 + l15][ks * 32 + q3 * 8];
                short8 pl = *(const short8*)&Plds[wv][1][gt * 16 + l15][ks * 32 + q3 * 8];
                Oacc[gt] = __builtin_amdgcn_mfma_f32_16x16x32_bf16(vh, ph, Oacc[gt], 0, 0, 0);
                Oacc[gt] = __builtin_amdgcn_mfma_f32_16x16x32_bf16(vh, pl, Oacc[gt], 0, 0, 0);
                Oacc[gt] = __builtin_amdgcn_mfma_f32_16x16x32_bf16(vl, ph, Oacc[gt], 0, 0, 0);
            }
        }
    }

    size_t obase = (((size_t)s4 * 64 + b) * 8 + h);
#pragma unroll
    for (int gt = 0; gt < 2; ++gt) {
        float z = zacc[gt];
        z += __shfl_xor(z, 16);
        z += __shfl_xor(z, 32);
        int g = wv * 32 + gt * 16 + l15;
        if (q3 == 0) Zpart[obase * 128 + g] = z;
#pragma unroll
        for (int r = 0; r < 4; ++r) {
            int d = q3 * 4 + r;
            Opart[(obase * 16 + d) * 128 + g] = Oacc[gt][r];
        }
    }
}

// ---- K7b: combine partials -> MHt[b][h*16+d][g] ----
__global__ __launch_bounds__(256) void k_ocomb(const float* Opart, const float* Zpart, float* MHt) {
    int bh = blockIdx.x;
    int b = bh >> 3, h = bh & 7;
    int tid = threadIdx.x;
    for (int e = tid; e < 2048; e += 256) {
        int d = e >> 7, g = e & 127;
        float z = 0.0f, o = 0.0f;
#pragma unroll
        for (int s = 0; s < 4; ++s) {
            z += Zpart[(((size_t)s * 64 + b) * 8 + h) * 128 + g];
            o += Opart[((((size_t)s * 64 + b) * 8 + h) * 16 + d) * 128 + g];
        }
        MHt[((size_t)b * 128 + h * 16 + d) * 128 + g] = o / z;
    }
}

// ---- K8: FQhl[b][g][c] (bf16 hi/lo) = (MH[b][g]@WcT + bc)*rsqrt(H) ----
__global__ __launch_bounds__(256) void k_fq(const float* MHt, const float* WT, const float* bcv,
                                            unsigned short* FQhi, unsigned short* FQlo) {
    int b = blockIdx.x;
    int tid = threadIdx.x, xq = tid & 15, yq = tid >> 4;
    __shared__ float Bl[128 * 132];
    for (int e = tid; e < 16384; e += 256) {
        int j = e >> 7, g = e & 127;
        Bl[j * 132 + g] = MHt[(size_t)b * 16384 + e];
    }
    __syncthreads();
    const float* Wc = WT + 6 * 16384;
    float acc[8][8] = {};
#pragma unroll 4
    for (int j = 0; j < 128; ++j) {
        const float4* Ar = (const float4*)(Wc + j * 128);
        float4 a0 = Ar[yq], a1 = Ar[16 + yq];
        const float4* Br = (const float4*)(Bl + j * 132);
        float4 b0 = Br[xq], b1 = Br[16 + xq];
        fma8x8(a0, a1, b0, b1, acc);
    }
    float4 bc0 = *(const float4*)(bcv + 4 * yq);
    float4 bc1 = *(const float4*)(bcv + 64 + 4 * yq);
    const float bcv8[8] = {bc0.x, bc0.y, bc0.z, bc0.w, bc1.x, bc1.y, bc1.z, bc1.w};
    const float sc = 0.08838834764831845f;  // 1/sqrt(128)
#pragma unroll
    for (int k = 0; k < 8; ++k) {
        int g = (k < 4) ? (4 * xq + k) : (64 + 4 * xq + (k - 4));
        size_t base = ((size_t)b * 128 + g) * 128;
        unsigned short h4[4], l4[4];
#pragma unroll
        for (int i = 0; i < 4; ++i) {
            float f = (acc[i][k] + bcv8[i]) * sc;
            h4[i] = bf16hi(f); l4[i] = bf16hi(f - bf16tof(h4[i]));
        }
        uint2 ph, pl;
        ph.x = h4[0] | (h4[1] << 16); ph.y = h4[2] | (h4[3] << 16);
        pl.x = l4[0] | (l4[1] << 16); pl.y = l4[2] | (l4[3] << 16);
        *(uint2*)(FQhi + base + 4 * yq) = ph;
        *(uint2*)(FQlo + base + 4 * yq) = pl;
#pragma unroll
        for (int i = 0; i < 4; ++i) {
            float f = (acc[4 + i][k] + bcv8[4 + i]) * sc;
            h4[i] = bf16hi(f); l4[i] = bf16hi(f - bf16tof(h4[i]));
        }
        ph.x = h4[0] | (h4[1] << 16); ph.y = h4[2] | (h4[3] << 16);
        pl.x = l4[0] | (l4[1] << 16); pl.y = l4[2] | (l4[3] << 16);
        *(uint2*)(FQhi + base + 64 + 4 * yq) = ph;
        *(uint2*)(FQlo + base + 64 + 4 * yq) = pl;
    }
}

// ---- K9: logits via split-bf16 MFMA; swapped operands; no LDS, no barriers ----
__global__ __launch_bounds__(256, 4) void k_logits(const float* emb,
        const unsigned short* FQhi, const unsigned short* FQlo,
        const unsigned long long* bits, float* out, float* Zp) {
    int nt = blockIdx.x, b = blockIdx.y;  // nt in [0,16)
    int tid = threadIdx.x;
    int wv = tid >> 6, lane = tid & 63, l15 = lane & 15, q3 = lane >> 4;
    int n0 = nt * 128;

    short8 beh[2][4], bel[2][4];
#pragma unroll
    for (int t = 0; t < 2; ++t) {
        int n = n0 + wv * 32 + t * 16 + l15;
        const float* rowp = emb + ((size_t)b * NN + n) * HH + q3 * 8;
        bool ok = (n < NN);
#pragma unroll
        for (int ks = 0; ks < 4; ++ks) {
            float4 v0 = make_float4(0.f, 0.f, 0.f, 0.f), v1 = v0;
            if (ok) {
                v0 = *(const float4*)(rowp + ks * 32);
                v1 = *(const float4*)(rowp + ks * 32 + 4);
            }
            cvt8(v0, v1, beh[t][ks], bel[t][ks]);
        }
    }

    const unsigned long long* bb = bits + (size_t)b * 128 * 32;
    int g = 0;
#pragma unroll
    for (int gt = 0; gt < 8; ++gt) {
        f32x4 acc[2] = {{0.f, 0.f, 0.f, 0.f}, {0.f, 0.f, 0.f, 0.f}};
#pragma unroll
        for (int ks = 0; ks < 4; ++ks) {
            size_t foff = ((size_t)b * 128 + gt * 16 + l15) * 128 + ks * 32 + q3 * 8;
            short8 fh = *(const short8*)(FQhi + foff);
            short8 fl = *(const short8*)(FQlo + foff);
#pragma unroll
            for (int t = 0; t < 2; ++t) {
                acc[t] = __builtin_amdgcn_mfma_f32_16x16x32_bf16(beh[t][ks], fh, acc[t], 0, 0, 0);
                acc[t] = __builtin_amdgcn_mfma_f32_16x16x32_bf16(bel[t][ks], fh, acc[t], 0, 0, 0);
                acc[t] = __builtin_amdgcn_mfma_f32_16x16x32_bf16(beh[t][ks], fl, acc[t], 0, 0, 0);
            }
        }
        g = gt * 16 + l15;
        float psum = 0.f;
#pragma unroll
        for (int t = 0; t < 2; ++t) {
            int nb = n0 + wv * 32 + t * 16 + 4 * q3;
            int word = (n0 + wv * 32 + t * 16) >> 6;
            unsigned long long wm = bb[g * 32 + word];
            float pv[4];
#pragma unroll
            for (int r = 0; r < 4; ++r) {
                int n = nb + r;
                float l = acc[t][r];
                float e2 = __expf(2.0f * l);
                float th = 1.0f - 2.0f / (e2 + 1.0f);
                float p = ((wm >> (n & 63)) & 1ull) ? __expf(10.0f * th) : 0.0f;
                pv[r] = p;
                psum += p;
            }
            if (nb + 3 < NN) {
                *(float4*)(out + ((size_t)b * 128 + g) * NN + nb) =
                    make_float4(pv[0], pv[1], pv[2], pv[3]);
            }
        }
        psum += __shfl_xor(psum, 16);
        psum += __shfl_xor(psum, 32);
        if (q3 == 0) Zp[((size_t)(nt * 4 + wv)) * 8192 + b * 128 + g] = psum;
    }
}

// ---- K10: normalize probs (64 partial-sum slots) ----
__global__ __launch_bounds__(256) void k_norm(const float* Zp, float* out) {
    int bg = blockIdx.x;
    __shared__ float invs;
    if (threadIdx.x == 0) {
        float s = 0.0f;
#pragma unroll
        for (int t = 0; t < 64; ++t) s += Zp[(size_t)t * 8192 + bg];
        invs = 1.0f / s;
    }
    __syncthreads();
    float inv = invs;
    for (int n = threadIdx.x; n < NN; n += 256) out[(size_t)bg * NN + n] *= inv;
}

extern "C" void kernel_launch(void* const* d_in, const int* in_sizes, int n_in,
                              void* d_out, int out_size, void* d_ws, size_t ws_size,
                              hipStream_t stream) {
    const float* emb = (const float*)d_in[0];
    const float* mask = (const float*)d_in[1];
    const float* Wqg = (const float*)d_in[2];
    const float* Wqs = (const float*)d_in[3];
    const float* Wqt = (const float*)d_in[4];
    const float* Wql = (const float*)d_in[5];
    const float* Wk = (const float*)d_in[6];
    const float* Wv = (const float*)d_in[7];
    const float* Wc = (const float*)d_in[8];
    const float* bc = (const float*)d_in[9];
    const int* srcn = (const int*)d_in[10];
    const int* tgtn = (const int*)d_in[11];
    const int* lastn = (const int*)d_in[12];
    float* out = (float*)d_out;

    // ---- workspace map (float offsets); K/V = 8,192,000 floats EACH ----
    float* ws = (float*)d_ws;
    float* WT = ws;                                   // [0, 114688)
    unsigned short* Wkhi = (unsigned short*)(WT + 4 * 16384);
    unsigned short* Wklo = Wkhi + 16384;
    unsigned short* Wvhi = Wklo + 16384;
    unsigned short* Wvlo = Wvhi + 16384;
    float* gpart = ws + 114688;                       // [114688, 245760)
    float* qbase = ws + 245760;                       // [245760, 253952)
    float* MHt = ws + 253952;                         // [253952, 1302528)
    unsigned short* FQhi = (unsigned short*)(ws + 1302528);     // [1302528, 2351104)
    unsigned short* FQlo = FQhi + 1048576;
    float* Zp = ws + 2351104;                         // [2351104, 3399680)
    unsigned short* Khi = (unsigned short*)(ws + 3399680);      // [3399680, 11591680)
    unsigned short* Klo = (unsigned short*)(ws + 11591680);     // [11591680, 19783680)
    unsigned short* Vhi = (unsigned short*)(ws + 19783680);     // [19783680, 27975680)
    unsigned short* Vlo = (unsigned short*)(ws + 27975680);     // [27975680, 36167680)
    unsigned long long* bits = (unsigned long long*)(ws + 36167680);  // [36167680, 36691968)

    // flash partials + Q live in d_out (all consumed before k_logits writes it)
    float* Opart = out;                               // [0, 4194304)
    float* Zpart = out + 4194304;                     // [4194304, 4456448)
    unsigned short* Qhi = (unsigned short*)(out + 4456448);     // [4456448, 4980736)
    unsigned short* Qlo = Qhi + 1048576;                        // [4980736, 5505024)

    k_wt<<<7, 256, 0, stream>>>(Wqg, Wqs, Wqt, Wql, Wk, Wv, Wc, WT, Wkhi, Wklo, Wvhi, Wvlo);
    k_maskbits<<<8192, 256, 0, stream>>>(mask, bits);
    k_gsum<<<dim3(16, 64), 128, 0, stream>>>(emb, gpart);
    k_kv<<<dim3(16, 64), 256, 0, stream>>>(emb, Wkhi, Wklo, Wvhi, Wvlo, Khi, Klo, Vhi, Vlo);
    k_qbase<<<64, 128, 0, stream>>>(emb, srcn, tgtn, gpart, WT, qbase);
    k_qlast<<<64, 256, 0, stream>>>(emb, lastn, WT, qbase, Qhi, Qlo);
    k_flash<<<2048, 256, 0, stream>>>(Khi, Klo, Vhi, Vlo, Qhi, Qlo, bits, Opart, Zpart);
    k_ocomb<<<512, 256, 0, stream>>>(Opart, Zpart, MHt);
    k_fq<<<64, 256, 0, stream>>>(MHt, WT, bc, FQhi, FQlo);
    k_logits<<<dim3(16, 64), 256, 0, stream>>>(emb, FQhi, FQlo, bits, out, Zp);
    k_norm<<<8192, 256, 0, stream>>>(Zp, out);
}

// Round 15
// 347.366 us; speedup vs baseline: 1.9505x; 1.0584x over previous
//
#include <hip/hip_runtime.h>
#include <hip/hip_bf16.h>

#define BB 64
#define NN 2000
#define GG 128
#define HH 128
#define NHEAD 8
#define HD 16

typedef __attribute__((ext_vector_type(8))) short short8;
typedef __attribute__((ext_vector_type(4))) float f32x4;

__device__ __forceinline__ unsigned short bf16hi(float f) {
    union { float f; unsigned u; } v; v.f = f;
    return (unsigned short)(v.u >> 16);
}
__device__ __forceinline__ float bf16tof(unsigned short h) {
    union { float f; unsigned u; } v; v.u = ((unsigned)h) << 16;
    return v.f;
}

// convert 8 fp32 (two float4) -> bf16 hi/lo short8 pair
__device__ __forceinline__ void cvt8(const float4& v0, const float4& v1,
                                     short8& hi, short8& lo) {
    float fv[8] = {v0.x, v0.y, v0.z, v0.w, v1.x, v1.y, v1.z, v1.w};
#pragma unroll
    for (int i = 0; i < 8; ++i) {
        unsigned short h = bf16hi(fv[i]);
        hi[i] = (short)h;
        lo[i] = (short)bf16hi(fv[i] - bf16tof(h));
    }
}

__device__ __forceinline__ void fma8x8(const float4& a0, const float4& a1,
                                       const float4& b0, const float4& b1,
                                       float acc[8][8]) {
    const float av[8] = {a0.x, a0.y, a0.z, a0.w, a1.x, a1.y, a1.z, a1.w};
    const float bv[8] = {b0.x, b0.y, b0.z, b0.w, b1.x, b1.y, b1.z, b1.w};
#pragma unroll
    for (int i = 0; i < 8; ++i)
#pragma unroll
        for (int k = 0; k < 8; ++k) acc[i][k] += av[i] * bv[k];
}

// ---- K1: transpose Wqg,Wqs,Wqt,Wql,Wc (fp32) + convert Wk,Wv to bf16 hi/lo ----
__global__ __launch_bounds__(256) void k_wt(const float* w0, const float* w1, const float* w2,
                     const float* w3, const float* w4, const float* w5,
                     const float* w6, float* WT,
                     unsigned short* Wkhi, unsigned short* Wklo,
                     unsigned short* Wvhi, unsigned short* Wvlo) {
    int m = blockIdx.x;
    if (m >= 5) {
        const float* src = (m == 5) ? w4 : w5;
        unsigned short* dh = (m == 5) ? Wkhi : Wvhi;
        unsigned short* dl = (m == 5) ? Wklo : Wvlo;
        for (int e = threadIdx.x * 4; e < 16384; e += 1024) {
            float4 v = *(const float4*)(src + e);
            float fv[4] = {v.x, v.y, v.z, v.w};
            unsigned short h4[4], l4[4];
#pragma unroll
            for (int i = 0; i < 4; ++i) {
                h4[i] = bf16hi(fv[i]); l4[i] = bf16hi(fv[i] - bf16tof(h4[i]));
            }
            uint2 ph, pl;
            ph.x = h4[0] | (h4[1] << 16); ph.y = h4[2] | (h4[3] << 16);
            pl.x = l4[0] | (l4[1] << 16); pl.y = l4[2] | (l4[3] << 16);
            *(uint2*)(dh + e) = ph;
            *(uint2*)(dl + e) = pl;
        }
        return;
    }
    __shared__ float t[128 * 129];
    const float* src = (m == 0) ? w0 : (m == 1) ? w1 : (m == 2) ? w2 : (m == 3) ? w3 : w6;
    int slot = (m == 4) ? 6 : m;
    for (int e = threadIdx.x; e < 16384; e += 256) {
        int c = e >> 7, j = e & 127;
        t[c * 129 + j] = src[e];
    }
    __syncthreads();
    for (int e = threadIdx.x; e < 16384; e += 256) {
        int j = e >> 7, c = e & 127;
        WT[slot * 16384 + e] = t[c * 129 + j];
    }
}

// ---- K2: mask -> bitmask ----
__global__ __launch_bounds__(256) void k_maskbits(const float* mask, unsigned long long* bits) {
    int bg = blockIdx.x;
    int lane = threadIdx.x & 63;
    int wv = threadIdx.x >> 6;
    for (int w = wv; w < 32; w += 4) {
        int n = w * 64 + lane;
        bool keep = false;
        if (n < NN) keep = (mask[(size_t)bg * NN + n] == 0.0f);
        unsigned long long bal = __ballot(keep);
        if (lane == 0) bits[bg * 32 + w] = bal;
    }
}

// ---- K3: partial column sums of embeddings ----
__global__ __launch_bounds__(128) void k_gsum(const float* emb, float* gpart) {
    int ck = blockIdx.x, b = blockIdx.y, c = threadIdx.x;
    const float* p = emb + ((size_t)b * NN + ck * 125) * HH + c;
    float s = 0.0f;
#pragma unroll 5
    for (int r = 0; r < 125; ++r) s += p[(size_t)r * HH];
    gpart[ck * 8192 + b * 128 + c] = s;
}

// ---- K4: qbase ----
__global__ __launch_bounds__(128) void k_qbase(const float* emb, const int* srcn, const int* tgtn,
                        const float* gpart, const float* WT, float* qbase) {
    int b = blockIdx.x, c = threadIdx.x;
    __shared__ float ge[128], se[128], te[128];
    float s = 0.0f;
#pragma unroll
    for (int t = 0; t < 16; ++t) s += gpart[t * 8192 + b * 128 + c];
    ge[c] = s * (1.0f / 2000.0f);
    se[c] = emb[((size_t)b * NN + srcn[b]) * HH + c];
    te[c] = emb[((size_t)b * NN + tgtn[b]) * HH + c];
    __syncthreads();
    const float* Wg = WT;
    const float* Ws = WT + 16384;
    const float* Wt2 = WT + 32768;
    float acc = 0.0f;
#pragma unroll 4
    for (int j = 0; j < 128; ++j) {
        acc += ge[j] * Wg[j * 128 + c] + se[j] * Ws[j * 128 + c] + te[j] * Wt2[j * 128 + c];
    }
    qbase[b * 128 + c] = acc;
}

// ---- K5: Qhl[b][g][128] (bf16 hi/lo) = SCALE*(qbase + lastemb@WqlT) ----
// SCALE = 0.25 * log2(e): folds the exp->exp2 conversion into Q so k_flash
// can use raw v_exp_f32 (exp2) without a per-element multiply.
__global__ __launch_bounds__(256) void k_qlast(const float* emb, const int* lastn, const float* WT,
                        const float* qbase, unsigned short* Qhi, unsigned short* Qlo) {
    int b = blockIdx.x;
    int tid = threadIdx.x, xq = tid & 15, yq = tid >> 4;
    __shared__ float Bl[128 * 132];
    for (int e = tid; e < 16384; e += 256) {
        int g = e >> 7, j = e & 127;
        Bl[j * 132 + g] = emb[((size_t)b * NN + lastn[b * 128 + g]) * HH + j];
    }
    __syncthreads();
    const float* Wql = WT + 3 * 16384;
    float acc[8][8] = {};
#pragma unroll 4
    for (int j = 0; j < 128; ++j) {
        const float4* Ar = (const float4*)(Wql + j * 128);
        float4 a0 = Ar[yq], a1 = Ar[16 + yq];
        const float4* Br = (const float4*)(Bl + j * 132);
        float4 b0 = Br[xq], b1 = Br[16 + xq];
        fma8x8(a0, a1, b0, b1, acc);
    }
    const float QSC = 0.36067376022224085f;  // 0.25 * log2(e)
    float4 qb0 = *(const float4*)(qbase + b * 128 + 4 * yq);
    float4 qb1 = *(const float4*)(qbase + b * 128 + 64 + 4 * yq);
    const float q0v[4] = {qb0.x, qb0.y, qb0.z, qb0.w};
    const float q1v[4] = {qb1.x, qb1.y, qb1.z, qb1.w};
#pragma unroll
    for (int k = 0; k < 8; ++k) {
        int g = (k < 4) ? (4 * xq + k) : (64 + 4 * xq + (k - 4));
        size_t base = ((size_t)b * 128 + g) * 128;
        unsigned short h4[4], l4[4];
#pragma unroll
        for (int i = 0; i < 4; ++i) {
            float f = (acc[i][k] + q0v[i]) * QSC;
            h4[i] = bf16hi(f); l4[i] = bf16hi(f - bf16tof(h4[i]));
        }
        uint2 ph, pl;
        ph.x = h4[0] | (h4[1] << 16); ph.y = h4[2] | (h4[3] << 16);
        pl.x = l4[0] | (l4[1] << 16); pl.y = l4[2] | (l4[3] << 16);
        *(uint2*)(Qhi + base + 4 * yq) = ph;
        *(uint2*)(Qlo + base + 4 * yq) = pl;
#pragma unroll
        for (int i = 0; i < 4; ++i) {
            float f = (acc[4 + i][k] + q1v[i]) * QSC;
            h4[i] = bf16hi(f); l4[i] = bf16hi(f - bf16tof(h4[i]));
        }
        ph.x = h4[0] | (h4[1] << 16); ph.y = h4[2] | (h4[3] << 16);
        pl.x = l4[0] | (l4[1] << 16); pl.y = l4[2] | (l4[3] << 16);
        *(uint2*)(Qhi + base + 64 + 4 * yq) = ph;
        *(uint2*)(Qlo + base + 64 + 4 * yq) = pl;
    }
}

// ---- K6: K/V projections via split-bf16 MFMA; 128-n tile, no LDS, no barriers ----
__global__ __launch_bounds__(256, 4) void k_kv(const float* emb,
        const unsigned short* Wkhi, const unsigned short* Wklo,
        const unsigned short* Wvhi, const unsigned short* Wvlo,
        unsigned short* Khi, unsigned short* Klo,
        unsigned short* Vhi, unsigned short* Vlo) {
    int nt = blockIdx.x, b = blockIdx.y;  // nt in [0,16)
    int tid = threadIdx.x;
    int wv = tid >> 6, lane = tid & 63, l15 = lane & 15, q3 = lane >> 4;
    int n0 = nt * 128;

    short8 eh[2][4], el[2][4];
#pragma unroll
    for (int t = 0; t < 2; ++t) {
        int n = n0 + wv * 32 + t * 16 + l15;
        const float* rowp = emb + ((size_t)b * NN + n) * HH + q3 * 8;
        bool ok = (n < NN);
#pragma unroll
        for (int ks = 0; ks < 4; ++ks) {
            float4 v0 = make_float4(0.f, 0.f, 0.f, 0.f), v1 = v0;
            if (ok) {
                v0 = *(const float4*)(rowp + ks * 32);
                v1 = *(const float4*)(rowp + ks * 32 + 4);
            }
            cvt8(v0, v1, eh[t][ks], el[t][ks]);
        }
    }

#pragma unroll
    for (int ct = 0; ct < 8; ++ct) {
        f32x4 aK[2] = {{0.f, 0.f, 0.f, 0.f}, {0.f, 0.f, 0.f, 0.f}};
        f32x4 aV[2] = {{0.f, 0.f, 0.f, 0.f}, {0.f, 0.f, 0.f, 0.f}};
#pragma unroll
        for (int ks = 0; ks < 4; ++ks) {
            size_t woff = ((size_t)(ct * 16 + l15)) * 128 + ks * 32 + q3 * 8;
            short8 wkh = *(const short8*)(Wkhi + woff);
            short8 wkl = *(const short8*)(Wklo + woff);
            short8 wvh = *(const short8*)(Wvhi + woff);
            short8 wvl = *(const short8*)(Wvlo + woff);
#pragma unroll
            for (int t = 0; t < 2; ++t) {
                aK[t] = __builtin_amdgcn_mfma_f32_16x16x32_bf16(wkh, eh[t][ks], aK[t], 0, 0, 0);
                aK[t] = __builtin_amdgcn_mfma_f32_16x16x32_bf16(wkh, el[t][ks], aK[t], 0, 0, 0);
                aK[t] = __builtin_amdgcn_mfma_f32_16x16x32_bf16(wkl, eh[t][ks], aK[t], 0, 0, 0);
                aV[t] = __builtin_amdgcn_mfma_f32_16x16x32_bf16(eh[t][ks], wvh, aV[t], 0, 0, 0);
                aV[t] = __builtin_amdgcn_mfma_f32_16x16x32_bf16(el[t][ks], wvh, aV[t], 0, 0, 0);
                aV[t] = __builtin_amdgcn_mfma_f32_16x16x32_bf16(eh[t][ks], wvl, aV[t], 0, 0, 0);
            }
        }
#pragma unroll
        for (int t = 0; t < 2; ++t) {
            int kn = n0 + wv * 32 + t * 16 + l15;
            if (kn < NN) {
                unsigned short h4[4], l4[4];
#pragma unroll
                for (int r = 0; r < 4; ++r) {
                    float f = aK[t][r];
                    h4[r] = bf16hi(f); l4[r] = bf16hi(f - bf16tof(h4[r]));
                }
                uint2 ph, pl;
                ph.x = h4[0] | (h4[1] << 16); ph.y = h4[2] | (h4[3] << 16);
                pl.x = l4[0] | (l4[1] << 16); pl.y = l4[2] | (l4[3] << 16);
                size_t kbase = (((size_t)b * 8 + ct) * 2000 + kn) * 16 + 4 * q3;
                *(uint2*)(Khi + kbase) = ph;
                *(uint2*)(Klo + kbase) = pl;
            }
            int nb = n0 + wv * 32 + t * 16 + 4 * q3;
            if (nb + 3 < NN) {
                unsigned short h4[4], l4[4];
#pragma unroll
                for (int r = 0; r < 4; ++r) {
                    float f = aV[t][r];
                    h4[r] = bf16hi(f); l4[r] = bf16hi(f - bf16tof(h4[r]));
                }
                uint2 ph, pl;
                ph.x = h4[0] | (h4[1] << 16); ph.y = h4[2] | (h4[3] << 16);
                pl.x = l4[0] | (l4[1] << 16); pl.y = l4[2] | (l4[3] << 16);
                size_t vbase = (((size_t)b * 8 + ct) * 16 + l15) * 2000 + nb;
                *(uint2*)(Vhi + vbase) = ph;
                *(uint2*)(Vlo + vbase) = pl;
            }
        }
    }
}

// ---- K7: MFMA flash attention (round-10 staged structure; exp2 with pre-scaled Q) ----
__global__ __launch_bounds__(256) void k_flash(const unsigned short* Khi, const unsigned short* Klo,
                        const unsigned short* Vhi, const unsigned short* Vlo,
                        const unsigned short* Qhi, const unsigned short* Qlo,
                        const unsigned long long* bits, float* Opart, float* Zpart) {
    int bid = blockIdx.x;
    int s4 = bid & 3, h = (bid >> 2) & 7, b = bid >> 5;
    int tid = threadIdx.x;
    int wv = tid >> 6, lane = tid & 63, l15 = lane & 15, q3 = lane >> 4;

    __shared__ unsigned short Klds[2][64][24];
    __shared__ unsigned short Vlds[2][16][72];
    __shared__ unsigned short Plds[4][2][32][72];

    const short8 z8 = {0, 0, 0, 0, 0, 0, 0, 0};

    short8 qf[2][2];
#pragma unroll
    for (int gt = 0; gt < 2; ++gt) {
        int g = wv * 32 + gt * 16 + l15;
        if (q3 < 2) {
            size_t off = ((size_t)b * 128 + g) * 128 + h * 16 + q3 * 8;
            qf[gt][0] = *(const short8*)(Qhi + off);
            qf[gt][1] = *(const short8*)(Qlo + off);
        } else {
            qf[gt][0] = z8; qf[gt][1] = z8;
        }
    }

    f32x4 Oacc[2] = {{0.f, 0.f, 0.f, 0.f}, {0.f, 0.f, 0.f, 0.f}};
    float zacc[2] = {0.f, 0.f};

    const unsigned long long* bb0 = bits + (((size_t)b * 128 + wv * 32 + l15) * 32);
    const unsigned long long* bb1 = bb0 + 16 * 32;

    size_t kvbase = ((size_t)b * 8 + h);
    const unsigned short* Kh = Khi + kvbase * 32000;
    const unsigned short* Kl = Klo + kvbase * 32000;
    const unsigned short* Vh = Vhi + kvbase * 32000;
    const unsigned short* Vl = Vlo + kvbase * 32000;

    int snr = tid >> 2, sj4 = (tid & 3) * 4;
    int svd = tid >> 4, svn = (tid & 15) * 4;

    for (int ch = s4 * 8; ch < s4 * 8 + 8; ++ch) {
        int n0 = ch * 64;
        __syncthreads();
        {
            uint2 zz; zz.x = 0; zz.y = 0;
            int n = n0 + snr;
            uint2 k0 = zz, k1 = zz;
            if (n < NN) {
                size_t off = ((size_t)n) * 16 + sj4;
                k0 = *(const uint2*)(Kh + off);
                k1 = *(const uint2*)(Kl + off);
            }
            *(uint2*)&Klds[0][snr][sj4] = k0;
            *(uint2*)&Klds[1][snr][sj4] = k1;
            int vn = n0 + svn;
            uint2 v0 = zz, v1 = zz;
            if (vn + 3 < NN) {
                size_t off = ((size_t)svd) * 2000 + vn;
                v0 = *(const uint2*)(Vh + off);
                v1 = *(const uint2*)(Vl + off);
            }
            *(uint2*)&Vlds[0][svd][svn] = v0;
            *(uint2*)&Vlds[1][svd][svn] = v1;
        }
        __syncthreads();

        unsigned long long wm0 = bb0[ch];
        unsigned long long wm1 = bb1[ch];

        f32x4 S[4][2];
#pragma unroll
        for (int nt = 0; nt < 4; ++nt) {
            short8 kh, kl;
            if (q3 < 2) {
                kh = *(const short8*)&Klds[0][nt * 16 + l15][q3 * 8];
                kl = *(const short8*)&Klds[1][nt * 16 + l15][q3 * 8];
            } else { kh = z8; kl = z8; }
#pragma unroll
            for (int gt = 0; gt < 2; ++gt) {
                f32x4 c = {0.f, 0.f, 0.f, 0.f};
                c = __builtin_amdgcn_mfma_f32_16x16x32_bf16(kh, qf[gt][0], c, 0, 0, 0);
                c = __builtin_amdgcn_mfma_f32_16x16x32_bf16(kh, qf[gt][1], c, 0, 0, 0);
                c = __builtin_amdgcn_mfma_f32_16x16x32_bf16(kl, qf[gt][0], c, 0, 0, 0);
                S[nt][gt] = c;
            }
        }

#pragma unroll
        for (int nt = 0; nt < 4; ++nt) {
#pragma unroll
            for (int gt = 0; gt < 2; ++gt) {
                unsigned long long wm = gt ? wm1 : wm0;
                float p[4];
#pragma unroll
                for (int r = 0; r < 4; ++r) {
                    int sh = nt * 16 + q3 * 4 + r;
                    // S pre-scaled by log2(e) -> raw exp2, no multiply
                    float e = ((wm >> sh) & 1ull) ? __builtin_amdgcn_exp2f(S[nt][gt][r]) : 0.0f;
                    p[r] = e;
                    zacc[gt] += e;
                }
                unsigned short h4[4], l4[4];
#pragma unroll
                for (int r = 0; r < 4; ++r) {
                    h4[r] = bf16hi(p[r]); l4[r] = bf16hi(p[r] - bf16tof(h4[r]));
                }
                uint2 ph, pl;
                ph.x = h4[0] | (h4[1] << 16); ph.y = h4[2] | (h4[3] << 16);
                pl.x = l4[0] | (l4[1] << 16); pl.y = l4[2] | (l4[3] << 16);
                *(uint2*)&Plds[wv][0][gt * 16 + l15][nt * 16 + q3 * 4] = ph;
                *(uint2*)&Plds[wv][1][gt * 16 + l15][nt * 16 + q3 * 4] = pl;
            }
        }

#pragma unroll
        for (int ks = 0; ks < 2; ++ks) {
            short8 vh = *(const short8*)&Vlds[0][l15][ks * 32 + q3 * 8];
            short8 vl = *(const short8*)&Vlds[1][l15][ks * 32 + q3 * 8];
#pragma unroll
            for (int gt = 0; gt < 2; ++gt) {
                short8 ph = *(const short8*)&Plds[wv][0][gt * 16 + l15][ks * 32 + q3 * 8];
                short8 pl = *(const short8*)&Plds[wv][1][gt * 16 + l15][ks * 32 + q3 * 8];
                Oacc[gt] = __builtin_amdgcn_mfma_f32_16x16x32_bf16(vh, ph, Oacc[gt], 0, 0, 0);
                Oacc[gt] = __builtin_amdgcn_mfma_f32_16x16x32_bf16(vh, pl, Oacc[gt], 0, 0, 0);
                Oacc[gt] = __builtin_amdgcn_mfma_f32_16x16x32_bf16(vl, ph, Oacc[gt], 0, 0, 0);
            }
        }
    }

    size_t obase = (((size_t)s4 * 64 + b) * 8 + h);
#pragma unroll
    for (int gt = 0; gt < 2; ++gt) {
        float z = zacc[gt];
        z += __shfl_xor(z, 16);
        z += __shfl_xor(z, 32);
        int g = wv * 32 + gt * 16 + l15;
        if (q3 == 0) Zpart[obase * 128 + g] = z;
#pragma unroll
        for (int r = 0; r < 4; ++r) {
            int d = q3 * 4 + r;
            Opart[(obase * 16 + d) * 128 + g] = Oacc[gt][r];
        }
    }
}

// ---- K8 (fused ocomb+fq): FQhl[b][g][c] = ((O/Z)[b][g]@WcT + bc)*rsqrt(H) ----
__global__ __launch_bounds__(256) void k_fq(const float* Opart, const float* Zpart,
                                            const float* WT, const float* bcv,
                                            unsigned short* FQhi, unsigned short* FQlo) {
    int b = blockIdx.x;
    int tid = threadIdx.x, xq = tid & 15, yq = tid >> 4;
    __shared__ float Bl[128 * 132];
    __shared__ float zinv[8][128];
    for (int e = tid; e < 1024; e += 256) {
        int h = e >> 7, g = e & 127;
        float z = 0.0f;
#pragma unroll
        for (int s = 0; s < 4; ++s)
            z += Zpart[(((size_t)s * 64 + b) * 8 + h) * 128 + g];
        zinv[h][g] = 1.0f / z;
    }
    __syncthreads();
    for (int e = tid; e < 16384; e += 256) {
        int j = e >> 7, g = e & 127;   // j = h*16+d
        int h = j >> 4, d = j & 15;
        float o = 0.0f;
#pragma unroll
        for (int s = 0; s < 4; ++s)
            o += Opart[((((size_t)s * 64 + b) * 8 + h) * 16 + d) * 128 + g];
        Bl[j * 132 + g] = o * zinv[h][g];
    }
    __syncthreads();
    const float* Wc = WT + 6 * 16384;
    float acc[8][8] = {};
#pragma unroll 4
    for (int j = 0; j < 128; ++j) {
        const float4* Ar = (const float4*)(Wc + j * 128);
        float4 a0 = Ar[yq], a1 = Ar[16 + yq];
        const float4* Br = (const float4*)(Bl + j * 132);
        float4 b0 = Br[xq], b1 = Br[16 + xq];
        fma8x8(a0, a1, b0, b1, acc);
    }
    float4 bc0 = *(const float4*)(bcv + 4 * yq);
    float4 bc1 = *(const float4*)(bcv + 64 + 4 * yq);
    const float bcv8[8] = {bc0.x, bc0.y, bc0.z, bc0.w, bc1.x, bc1.y, bc1.z, bc1.w};
    const float sc = 0.08838834764831845f;  // 1/sqrt(128)
#pragma unroll
    for (int k = 0; k < 8; ++k) {
        int g = (k < 4) ? (4 * xq + k) : (64 + 4 * xq + (k - 4));
        size_t base = ((size_t)b * 128 + g) * 128;
        unsigned short h4[4], l4[4];
#pragma unroll
        for (int i = 0; i < 4; ++i) {
            float f = (acc[i][k] + bcv8[i]) * sc;
            h4[i] = bf16hi(f); l4[i] = bf16hi(f - bf16tof(h4[i]));
        }
        uint2 ph, pl;
        ph.x = h4[0] | (h4[1] << 16); ph.y = h4[2] | (h4[3] << 16);
        pl.x = l4[0] | (l4[1] << 16); pl.y = l4[2] | (l4[3] << 16);
        *(uint2*)(FQhi + base + 4 * yq) = ph;
        *(uint2*)(FQlo + base + 4 * yq) = pl;
#pragma unroll
        for (int i = 0; i < 4; ++i) {
            float f = (acc[4 + i][k] + bcv8[4 + i]) * sc;
            h4[i] = bf16hi(f); l4[i] = bf16hi(f - bf16tof(h4[i]));
        }
        ph.x = h4[0] | (h4[1] << 16); ph.y = h4[2] | (h4[3] << 16);
        pl.x = l4[0] | (l4[1] << 16); pl.y = l4[2] | (l4[3] << 16);
        *(uint2*)(FQhi + base + 64 + 4 * yq) = ph;
        *(uint2*)(FQlo + base + 64 + 4 * yq) = pl;
    }
}

// ---- K9: logits via split-bf16 MFMA; swapped operands; rcp-based tanh ----
__global__ __launch_bounds__(256, 4) void k_logits(const float* emb,
        const unsigned short* FQhi, const unsigned short* FQlo,
        const unsigned long long* bits, float* out, float* Zp) {
    int nt = blockIdx.x, b = blockIdx.y;  // nt in [0,16)
    int tid = threadIdx.x;
    int wv = tid >> 6, lane = tid & 63, l15 = lane & 15, q3 = lane >> 4;
    int n0 = nt * 128;

    short8 beh[2][4], bel[2][4];
#pragma unroll
    for (int t = 0; t < 2; ++t) {
        int n = n0 + wv * 32 + t * 16 + l15;
        const float* rowp = emb + ((size_t)b * NN + n) * HH + q3 * 8;
        bool ok = (n < NN);
#pragma unroll
        for (int ks = 0; ks < 4; ++ks) {
            float4 v0 = make_float4(0.f, 0.f, 0.f, 0.f), v1 = v0;
            if (ok) {
                v0 = *(const float4*)(rowp + ks * 32);
                v1 = *(const float4*)(rowp + ks * 32 + 4);
            }
            cvt8(v0, v1, beh[t][ks], bel[t][ks]);
        }
    }

    const unsigned long long* bb = bits + (size_t)b * 128 * 32;
    int g = 0;
#pragma unroll
    for (int gt = 0; gt < 8; ++gt) {
        f32x4 acc[2] = {{0.f, 0.f, 0.f, 0.f}, {0.f, 0.f, 0.f, 0.f}};
#pragma unroll
        for (int ks = 0; ks < 4; ++ks) {
            size_t foff = ((size_t)b * 128 + gt * 16 + l15) * 128 + ks * 32 + q3 * 8;
            short8 fh = *(const short8*)(FQhi + foff);
            short8 fl = *(const short8*)(FQlo + foff);
#pragma unroll
            for (int t = 0; t < 2; ++t) {
                acc[t] = __builtin_amdgcn_mfma_f32_16x16x32_bf16(beh[t][ks], fh, acc[t], 0, 0, 0);
                acc[t] = __builtin_amdgcn_mfma_f32_16x16x32_bf16(bel[t][ks], fh, acc[t], 0, 0, 0);
                acc[t] = __builtin_amdgcn_mfma_f32_16x16x32_bf16(beh[t][ks], fl, acc[t], 0, 0, 0);
            }
        }
        g = gt * 16 + l15;
        float psum = 0.f;
#pragma unroll
        for (int t = 0; t < 2; ++t) {
            int nb = n0 + wv * 32 + t * 16 + 4 * q3;
            int word = (n0 + wv * 32 + t * 16) >> 6;
            unsigned long long wm = bb[g * 32 + word];
            float pv[4];
#pragma unroll
            for (int r = 0; r < 4; ++r) {
                int n = nb + r;
                float l = acc[t][r];
                float e2 = __expf(2.0f * l);
                // 10*tanh(l) = 10 - 20/(e2+1); use fast rcp instead of IEEE div
                float th10 = 10.0f - 20.0f * __builtin_amdgcn_rcpf(e2 + 1.0f);
                float p = ((wm >> (n & 63)) & 1ull) ? __expf(th10) : 0.0f;
                pv[r] = p;
                psum += p;
            }
            if (nb + 3 < NN) {
                *(float4*)(out + ((size_t)b * 128 + g) * NN + nb) =
                    make_float4(pv[0], pv[1], pv[2], pv[3]);
            }
        }
        psum += __shfl_xor(psum, 16);
        psum += __shfl_xor(psum, 32);
        if (q3 == 0) Zp[((size_t)(nt * 4 + wv)) * 8192 + b * 128 + g] = psum;
    }
}

// ---- K10: normalize probs (64 partial-sum slots, wave-parallel reduce) ----
__global__ __launch_bounds__(256) void k_norm(const float* Zp, float* out) {
    int bg = blockIdx.x;
    __shared__ float invs;
    int tid = threadIdx.x;
    if (tid < 64) {
        float s = Zp[(size_t)tid * 8192 + bg];
#pragma unroll
        for (int m = 1; m <= 32; m <<= 1) s += __shfl_xor(s, m);
        if (tid == 0) invs = 1.0f / s;
    }
    __syncthreads();
    float inv = invs;
    for (int n = tid; n < NN; n += 256) out[(size_t)bg * NN + n] *= inv;
}

extern "C" void kernel_launch(void* const* d_in, const int* in_sizes, int n_in,
                              void* d_out, int out_size, void* d_ws, size_t ws_size,
                              hipStream_t stream) {
    const float* emb = (const float*)d_in[0];
    const float* mask = (const float*)d_in[1];
    const float* Wqg = (const float*)d_in[2];
    const float* Wqs = (const float*)d_in[3];
    const float* Wqt = (const float*)d_in[4];
    const float* Wql = (const float*)d_in[5];
    const float* Wk = (const float*)d_in[6];
    const float* Wv = (const float*)d_in[7];
    const float* Wc = (const float*)d_in[8];
    const float* bc = (const float*)d_in[9];
    const int* srcn = (const int*)d_in[10];
    const int* tgtn = (const int*)d_in[11];
    const int* lastn = (const int*)d_in[12];
    float* out = (float*)d_out;

    // ---- workspace map (float offsets); K/V = 8,192,000 floats EACH ----
    float* ws = (float*)d_ws;
    float* WT = ws;                                   // [0, 114688)
    unsigned short* Wkhi = (unsigned short*)(WT + 4 * 16384);
    unsigned short* Wklo = Wkhi + 16384;
    unsigned short* Wvhi = Wklo + 16384;
    unsigned short* Wvlo = Wvhi + 16384;
    float* gpart = ws + 114688;                       // [114688, 245760)
    float* qbase = ws + 245760;                       // [245760, 253952)
    unsigned short* FQhi = (unsigned short*)(ws + 1302528);     // [1302528, 2351104)
    unsigned short* FQlo = FQhi + 1048576;
    float* Zp = ws + 2351104;                         // [2351104, 3399680)
    unsigned short* Khi = (unsigned short*)(ws + 3399680);      // [3399680, 11591680)
    unsigned short* Klo = (unsigned short*)(ws + 11591680);     // [11591680, 19783680)
    unsigned short* Vhi = (unsigned short*)(ws + 19783680);     // [19783680, 27975680)
    unsigned short* Vlo = (unsigned short*)(ws + 27975680);     // [27975680, 36167680)
    unsigned long long* bits = (unsigned long long*)(ws + 36167680);  // [36167680, 36691968)

    // flash partials + Q live in d_out (all consumed before k_logits writes it)
    float* Opart = out;                               // [0, 4194304)
    float* Zpart = out + 4194304;                     // [4194304, 4456448)
    unsigned short* Qhi = (unsigned short*)(out + 4456448);     // [4456448, 4980736)
    unsigned short* Qlo = Qhi + 1048576;                        // [4980736, 5505024)

    k_wt<<<7, 256, 0, stream>>>(Wqg, Wqs, Wqt, Wql, Wk, Wv, Wc, WT, Wkhi, Wklo, Wvhi, Wvlo);
    k_maskbits<<<8192, 256, 0, stream>>>(mask, bits);
    k_gsum<<<dim3(16, 64), 128, 0, stream>>>(emb, gpart);
    k_kv<<<dim3(16, 64), 256, 0, stream>>>(emb, Wkhi, Wklo, Wvhi, Wvlo, Khi, Klo, Vhi, Vlo);
    k_qbase<<<64, 128, 0, stream>>>(emb, srcn, tgtn, gpart, WT, qbase);
    k_qlast<<<64, 256, 0, stream>>>(emb, lastn, WT, qbase, Qhi, Qlo);
    k_flash<<<2048, 256, 0, stream>>>(Khi, Klo, Vhi, Vlo, Qhi, Qlo, bits, Opart, Zpart);
    k_fq<<<64, 256, 0, stream>>>(Opart, Zpart, WT, bc, FQhi, FQlo);
    k_logits<<<dim3(16, 64), 256, 0, stream>>>(emb, FQhi, FQlo, bits, out, Zp);
    k_norm<<<8192, 256, 0, stream>>>(Zp, out);
}